// Round 12
// baseline (630.314 us; speedup 1.0000x reference)
//
#include <hip/hip_runtime.h>

#define BATCH 16
#define CH 32
#define DC 3
#define SS 128
#define HH 255
#define RST 256                 // padded row stride (f16, 512B-aligned rows)
#define CST (HH*RST)            // channel stride in field
#define M1 12
#define M2 12
#define KY24 (2*M1)
#define NROWS (BATCH*CH*HH)
#define TWOPI_N 0.02463994238463573f   // 2*pi/255

typedef __attribute__((ext_vector_type(8))) _Float16 f16x8;
typedef __attribute__((ext_vector_type(4))) float f32x4;

// ---------------- mirror + fc0 lift (+ identity BN slot init) --------------
__global__ void __launch_bounds__(256) k_fc0(
    const float* __restrict__ x, const float* __restrict__ w,
    const float* __restrict__ bias, _Float16* __restrict__ h,
    float* __restrict__ bnp0){
  int y = blockIdx.x, b = blockIdx.y, xx = threadIdx.x;
  if (blockIdx.x == 0 && blockIdx.y == 0 && xx < CH){
    bnp0[xx] = 1.f; bnp0[CH+xx] = 0.f;
  }
  size_t base = (size_t)(b*CH*HH + y)*RST + xx;
  if (xx >= HH){                      // pad column -> zero
    for (int d=0; d<CH; d++) h[base + (size_t)d*CST] = (_Float16)0.f;
    return;
  }
  int iy = (y  >= SS-1) ? y  - (SS-1) : (SS-1) - y;
  int ix = (xx >= SS-1) ? xx - (SS-1) : (SS-1) - xx;
  float sgn = ((y >= SS-1) == (xx >= SS-1)) ? 1.f : -1.f;
  float v0 = sgn * x[((b*DC + 0)*SS + iy)*SS + ix];
  float v1 = sgn * x[((b*DC + 1)*SS + iy)*SS + ix];
  float v2 = sgn * x[((b*DC + 2)*SS + iy)*SS + ix];
  for (int d=0; d<CH; d++){
    float v = bias[d] + v0*w[d] + v1*w[CH+d] + v2*w[2*CH+d];
    h[base + (size_t)d*CST] = (_Float16)v;
  }
}

// ------- DFT weight fragments for k_dftw (B-fragment order, f16 hi/lo) -----
__global__ void __launch_bounds__(256) k_wgen(
    _Float16* __restrict__ Whi, _Float16* __restrict__ Wlo){
  int t = blockIdx.x*256 + threadIdx.x;
  if (t >= 2*8*64) return;
  int ct = t >> 9, ks = (t >> 6) & 7, lane = t & 63;
  int col = ct*16 + (lane & 15);
  int kb = ks*32 + (lane >> 4)*8;
  for (int j=0; j<8; j++){
    int k = kb + j;
    float w = 0.f;
    if (k < 255 && col < 24){
      int m = col >> 1;
      float ang = TWOPI_N * (float)((k*m) % 255);
      w = (col & 1) ? -sinf(ang) : cosf(ang);
    }
    _Float16 hi = (_Float16)w;
    Whi[t*8+j] = hi;
    Wlo[t*8+j] = (_Float16)(w - (float)hi);
  }
}

// ------- inverse-W twiddle table for k_fuse (B-fragment order, f16 hi/lo) --
__global__ void __launch_bounds__(256) k_tgen(
    _Float16* __restrict__ Th, _Float16* __restrict__ Tl){
  int t = blockIdx.x*256 + threadIdx.x;
  if (t >= 16*64) return;
  int ct = t >> 6, lane = t & 63;
  int xx = ct*16 + (lane & 15);
  int jbase = (lane >> 4)*8;
  for (int j=0; j<8; j++){
    int jg = jbase + j;
    float v = 0.f;
    if (xx < HH && jg <= 22){
      if (jg == 0) v = 1.f;
      else if (jg & 1){ int kx=(jg+1)>>1; v =  cosf(TWOPI_N*(float)((kx*xx)%255)); }
      else            { int kx= jg>>1;    v = -sinf(TWOPI_N*(float)((kx*xx)%255)); }
    }
    _Float16 hi = (_Float16)v;
    Th[t*8+j] = hi;
    Tl[t*8+j] = (_Float16)(v - (float)hi);
  }
}

// ------- fc1 weight fragments (B-fragment order, f16 hi/lo) ----------------
__global__ void __launch_bounds__(256) k_w1gen(
    const float* __restrict__ w1, _Float16* __restrict__ W1h,
    _Float16* __restrict__ W1l){
  int t = blockIdx.x*256 + threadIdx.x;
  if (t >= 8*64) return;
  int nt = t >> 6, lane = t & 63;
  int col = nt*16 + (lane & 15);
  int kb = (lane >> 4)*8;
  for (int j=0; j<8; j++){
    float v = w1[(kb+j)*128 + col];
    _Float16 hi = (_Float16)v;
    W1h[t*8+j] = hi;
    W1l[t*8+j] = (_Float16)(v - (float)hi);
  }
}

// ----- forward DFT along W via f16 MFMA (all data loads hoisted up front) --
__global__ void __launch_bounds__(256) k_dftw(
    const _Float16* __restrict__ h, float* __restrict__ R,
    const _Float16* __restrict__ Whi, const _Float16* __restrict__ Wlo,
    const float* __restrict__ bnp, int relu){
  int t = threadIdx.x;
  int wid = t >> 6, lane = t & 63;
  int r0 = blockIdx.x*64 + wid*16;
  int rowg = r0 + (lane & 15);
  int c = (rowg / HH) & (CH-1);
  _Float16 sch = (_Float16)bnp[c], shh = (_Float16)bnp[CH+c];
  f16x8 scv, shv;
  #pragma unroll
  for (int u=0; u<8; u++){ scv[u]=sch; shv[u]=shh; }
  const _Float16* rp = h + (size_t)rowg*RST;
  int koff = (lane >> 4)*8;
  // issue ALL 8 data loads first (fills the memory pipe)
  f16x8 av[8];
  #pragma unroll
  for (int ks=0; ks<8; ks++)
    av[ks] = *(const f16x8*)(rp + ks*32 + koff);
  f32x4 acc0 = {0.f,0.f,0.f,0.f};
  f32x4 acc1 = {0.f,0.f,0.f,0.f};
  #pragma unroll
  for (int ks=0; ks<8; ks++){
    f16x8 a = av[ks]*scv + shv;             // packed f16 BN
    if (relu){
      #pragma unroll
      for (int u=0; u<8; u++) a[u] = (a[u] > (_Float16)0.f) ? a[u] : (_Float16)0.f;
    }
    f16x8 b0h = *(const f16x8*)(Whi + ((size_t)(0*8+ks)*64 + lane)*8);
    f16x8 b0l = *(const f16x8*)(Wlo + ((size_t)(0*8+ks)*64 + lane)*8);
    f16x8 b1h = *(const f16x8*)(Whi + ((size_t)(1*8+ks)*64 + lane)*8);
    f16x8 b1l = *(const f16x8*)(Wlo + ((size_t)(1*8+ks)*64 + lane)*8);
    acc0 = __builtin_amdgcn_mfma_f32_16x16x32_f16(a, b0h, acc0, 0,0,0);
    acc0 = __builtin_amdgcn_mfma_f32_16x16x32_f16(a, b0l, acc0, 0,0,0);
    acc1 = __builtin_amdgcn_mfma_f32_16x16x32_f16(a, b1h, acc1, 0,0,0);
    acc1 = __builtin_amdgcn_mfma_f32_16x16x32_f16(a, b1l, acc1, 0,0,0);
  }
  int colq = lane & 15;
  int rq = r0 + (lane >> 4)*4;
  #pragma unroll
  for (int q=0; q<4; q++)
    R[(size_t)(rq+q)*24 + colq] = acc0[q];
  if (colq < 8){
    #pragma unroll
    for (int q=0; q<4; q++)
      R[(size_t)(rq+q)*24 + 16 + colq] = acc1[q];
  }
}

// ---------------- forward DFT along H: R -> Xf[bc][ky24][kx12], *1/255 -----
__global__ void __launch_bounds__(320) k_dfth(
    const float* __restrict__ R, float* __restrict__ Xf){
  __shared__ float lr[HH][M2][2];
  int t = threadIdx.x, bc = blockIdx.x;
  const float4* src = (const float4*)(R + bc*(HH*M2*2));
  for (int i=t; i<(HH*M2*2)/4; i+=320) ((float4*)lr)[i] = src[i];
  __syncthreads();
  if (t < KY24*M2){
    int ky = t / M2, kx = t - (t/M2)*M2;
    int freq = (ky < M1) ? ky : (HH - KY24 + ky);  // 0..11 or 243..254
    float ang = TWOPI_N * (float)freq;
    float c1 = cosf(ang), s1 = sinf(ang);
    float cr=1.f, sr=0.f, ar=0.f, ai=0.f;
    for (int y=0; y<HH; y++){
      float rr = lr[y][kx][0], ri = lr[y][kx][1];
      ar += rr*cr + ri*sr;   // * e^{-i theta}
      ai += ri*cr - rr*sr;
      float cn = cr*c1 - sr*s1;
      sr = sr*c1 + cr*s1;
      cr = cn;
    }
    const float inv = 1.0f/255.0f;
    int o = (bc*KY24 + ky)*(M2*2) + kx*2;
    Xf[o]   = ar*inv;
    Xf[o+1] = ai*inv;
  }
}

// ---------------- per-mode 32x32 complex channel mix -----------------------
__global__ void __launch_bounds__(384) k_mix(
    const float* __restrict__ Xf, const float* __restrict__ w,
    float* __restrict__ Y){
  int m2 = blockIdx.x, blk = blockIdx.y, b = blockIdx.z;
  int t = threadIdx.x;
  __shared__ float lx[CH][M1][2];
  for (int i=t; i<CH*M1*2; i+=384){
    int ii = i/(M1*2), rem = i - ii*(M1*2);
    int m1 = rem>>1, comp = rem&1;
    lx[ii][m1][comp] = Xf[((b*CH+ii)*KY24 + blk*M1 + m1)*(M2*2) + m2*2 + comp];
  }
  __syncthreads();
  int m1 = t >> 5, o = t & 31;
  float ar=0.f, ai=0.f;
  const float* wp = w + ((blk*CH*CH + o)*M1 + m1)*(M2*2) + m2*2;
  const int istride = CH*M1*M2*2;
  for (int i=0;i<CH;i++){
    float xr = lx[i][m1][0], xi = lx[i][m1][1];
    float wr = wp[0], wi = wp[1];
    ar += xr*wr - xi*wi;
    ai += xr*wi + xi*wr;
    wp += istride;
  }
  int oidx = ((b*CH+o)*KY24 + blk*M1 + m1)*(M2*2) + m2*2;
  Y[oidx]   = ar;
  Y[oidx+1] = ai;
}

// ---------------- inverse along H: Y modes -> G[bo][y][kx] -----------------
__global__ void __launch_bounds__(256) k_idfth(
    const float* __restrict__ Y, float* __restrict__ G){
  __shared__ float ly[KY24][M2][2];
  int t = threadIdx.x, bo = blockIdx.x;
  const float4* src = (const float4*)(Y + bo*(KY24*M2*2));
  for (int i=t; i<(KY24*M2*2)/4; i+=256) ((float4*)ly)[i] = src[i];
  __syncthreads();
  const float inv = 1.0f/255.0f;
  for (int p=t; p<HH*M2; p+=256){
    int y = p/M2, kx = p - (p/M2)*M2;
    float ang = TWOPI_N * (float)y;
    float c1 = cosf(ang), s1 = sinf(ang);
    float ar = ly[0][kx][0], ai = ly[0][kx][1];
    float c = c1, s = s1;
    #pragma unroll
    for (int k=1; k<=11; k++){
      float yr = ly[k][kx][0],     yi = ly[k][kx][1];
      ar += yr*c - yi*s;                 // * T_k
      ai += yr*s + yi*c;
      float zr = ly[24-k][kx][0],  zi = ly[24-k][kx][1];
      ar += zr*c + zi*s;                 // * conj(T_k)
      ai += zi*c - zr*s;
      float cn = c*c1 - s*s1;
      s = s*c1 + c*s1;
      c = cn;
    }
    {
      float zr = ly[12][kx][0], zi = ly[12][kx][1];   // freq -12: conj(T_12)
      ar += zr*c + zi*s;
      ai += zi*c - zr*s;
    }
    float f = (kx==0) ? inv : 2.0f*inv;
    int o = (bo*HH + y)*(M2*2) + kx*2;
    G[o]   = ar*f;
    G[o+1] = ai*f;
  }
}

// --- fused MFMA, 4-row pipelined block: conv + inv-W + partials ------------
// grid (64, BATCH); rows ybase..ybase+3 sequential, one 17.9KB LDS buffer;
// next-row field+G loads issued at top of current row (latency hidden).
__global__ void __launch_bounds__(256) k_fuse(
    const _Float16* __restrict__ h, const float* __restrict__ G,
    const float* __restrict__ cw, const float* __restrict__ cb,
    _Float16* __restrict__ tout, float* __restrict__ partials,
    const _Float16* __restrict__ Th, const _Float16* __restrict__ Tl,
    const float* __restrict__ bnp, int relu){
  __shared__ _Float16 buf[8448];   // Bf: (ct*65+lane)*8+j ; Of: o*264+xx
  __shared__ float red[CH][4][2];
  int t = threadIdx.x;
  // bijective XCD swizzle over 1024 blocks (1024 = 8*128)
  int bid = blockIdx.y*64 + blockIdx.x;
  int swz = (bid & 7)*128 + (bid >> 3);
  int b = swz >> 6, ybase = (swz & 63)*4;
  size_t hb0 = (size_t)(b*CH*HH)*RST;
  int w = t >> 6, lane = t & 63;
  int cS = t >> 5, xg = t & 31;
  int arow = lane & 15, koff = (lane >> 4)*8;

  // persistent conv A fragments (hi/lo), loaded once per block
  f16x8 a0h[2], a0l[2];
  #pragma unroll
  for (int rt=0; rt<2; rt++){
    int o = rt*16 + arow;
    #pragma unroll
    for (int j=0; j<8; j++){
      float v = cw[o*CH + koff + j];
      _Float16 hi = (_Float16)v;
      a0h[rt][j] = hi;
      a0l[rt][j] = (_Float16)(v - (float)hi);
    }
  }

  // prime the pipeline: row ybase
  f16x8 curF[4], nxtF[4], curG[2], nxtG[2];
  {
    int y = ybase;
    size_t hb = hb0 + (size_t)y*RST;
    #pragma unroll
    for (int it=0; it<4; it++)
      curF[it] = *(const f16x8*)(h + hb + (size_t)(it*8 + cS)*CST + xg*8);
    #pragma unroll
    for (int rt=0; rt<2; rt++){
      const float* gp = G + ((size_t)(b*CH + rt*16 + arow)*HH + y)*24;
      #pragma unroll
      for (int j=0; j<8; j++){
        int jg = koff + j;               // jg>=23: T rows are zero -> don't care
        curG[rt][j] = (_Float16)((jg==0) ? gp[0] : gp[jg+1]);
      }
    }
  }

  #pragma unroll 4
  for (int r=0; r<4; r++){
    int y = ybase + r;
    if (y >= HH) break;                  // block-uniform
    size_t hbase = hb0 + (size_t)y*RST;
    // --- issue next-row loads first (hidden under this row's work) ---
    if (r < 3){
      int yn = ybase + r + 1;
      int ycl = (yn < HH) ? yn : HH-1;   // clamp: value unused if invalid
      size_t hbn = hb0 + (size_t)ycl*RST;
      #pragma unroll
      for (int it=0; it<4; it++)
        nxtF[it] = *(const f16x8*)(h + hbn + (size_t)(it*8 + cS)*CST + xg*8);
      #pragma unroll
      for (int rt=0; rt<2; rt++){
        const float* gp = G + ((size_t)(b*CH + rt*16 + arow)*HH + ycl)*24;
        #pragma unroll
        for (int j=0; j<8; j++){
          int jg = koff + j;
          nxtG[rt][j] = (_Float16)((jg==0) ? gp[0] : gp[jg+1]);
        }
      }
    }
    // --- BN + scatter current row to LDS fragments ---
    #pragma unroll
    for (int it=0; it<4; it++){
      int c = it*8 + cS;
      _Float16 sc_ = (_Float16)bnp[c], sh_ = (_Float16)bnp[CH+c];
      f16x8 scv, shv;
      #pragma unroll
      for (int u=0; u<8; u++){ scv[u]=sc_; shv[u]=sh_; }
      f16x8 z = curF[it]*scv + shv;
      if (relu){
        #pragma unroll
        for (int u=0; u<8; u++) z[u] = (z[u] > (_Float16)0.f) ? z[u] : (_Float16)0.f;
      }
      int base = ((xg>>1)*65 + ((xg&1)*8) + ((c>>3)<<4))*8 + (c&7);
      #pragma unroll
      for (int u=0; u<8; u++) buf[base + u*8] = z[u];
    }
    __syncthreads();
    // --- MFMA: each wave owns 4 col-tiles (64 xx), all 32 output rows ---
    f32x4 acc[2][4];
    #pragma unroll
    for (int rt=0; rt<2; rt++)
      #pragma unroll
      for (int cl=0; cl<4; cl++) acc[rt][cl] = (f32x4){0.f,0.f,0.f,0.f};
    #pragma unroll
    for (int cl=0; cl<4; cl++){
      int ct = w*4 + cl;
      f16x8 bd = *(const f16x8*)(buf + ((size_t)ct*65 + lane)*8);
      f16x8 th = *(const f16x8*)(Th + ((size_t)ct*64 + lane)*8);
      f16x8 tl = *(const f16x8*)(Tl + ((size_t)ct*64 + lane)*8);
      #pragma unroll
      for (int rt=0; rt<2; rt++){
        acc[rt][cl] = __builtin_amdgcn_mfma_f32_16x16x32_f16(a0h[rt], bd, acc[rt][cl], 0,0,0);
        acc[rt][cl] = __builtin_amdgcn_mfma_f32_16x16x32_f16(a0l[rt], bd, acc[rt][cl], 0,0,0);
        acc[rt][cl] = __builtin_amdgcn_mfma_f32_16x16x32_f16(curG[rt], th, acc[rt][cl], 0,0,0);
        acc[rt][cl] = __builtin_amdgcn_mfma_f32_16x16x32_f16(curG[rt], tl, acc[rt][cl], 0,0,0);
      }
    }
    // --- BN partial sums from registers (exclude pad col) ---
    #pragma unroll
    for (int rt=0; rt<2; rt++)
      #pragma unroll
      for (int q=0; q<4; q++){
        float v1 = 0.f, v2 = 0.f;
        #pragma unroll
        for (int cl=0; cl<4; cl++){
          int xxo = (w*4 + cl)*16 + (lane & 15);
          int o = rt*16 + (lane >> 4)*4 + q;
          float v = acc[rt][cl][q] + cb[o];
          float vv = (xxo < HH) ? v : 0.f;
          v1 += vv; v2 += vv*vv;
        }
        #pragma unroll
        for (int off=8; off>0; off>>=1){
          v1 += __shfl_xor(v1, off, 16);
          v2 += __shfl_xor(v2, off, 16);
        }
        if ((lane & 15) == 0){
          int o = rt*16 + (lane >> 4)*4 + q;
          red[o][w][0] = v1;
          red[o][w][1] = v2;
        }
      }
    __syncthreads();    // Bf reads done -> safe to overwrite buf as Of
    #pragma unroll
    for (int rt=0; rt<2; rt++)
      #pragma unroll
      for (int cl=0; cl<4; cl++){
        int xxo = (w*4 + cl)*16 + (lane & 15);
        #pragma unroll
        for (int q=0; q<4; q++){
          int o = rt*16 + (lane >> 4)*4 + q;   // C/D layout (m89)
          buf[o*264 + xxo] = (_Float16)(acc[rt][cl][q] + cb[o]);
        }
      }
    __syncthreads();
    // --- coalesced f16x8 row stores (pad col written too; harmless) ---
    {
      int o = t >> 3, xb = (t & 7)*32;
      #pragma unroll
      for (int v4=0; v4<4; v4++){
        f16x8 vv = *(const f16x8*)(buf + o*264 + xb + v4*8);
        *(f16x8*)(tout + hbase + (size_t)o*CST + xb + v4*8) = vv;
      }
    }
    // --- contiguous 256B partials write ---
    if (t < CH*2){
      int oo = t >> 1, st = t & 1;
      float s = red[oo][0][st] + red[oo][1][st] + red[oo][2][st] + red[oo][3][st];
      partials[((size_t)b*HH + y)*64 + t] = s;
    }
    __syncthreads();    // Of reads done -> safe for next row's Bf scatter
    // --- rotate pipeline registers ---
    #pragma unroll
    for (int it=0; it<4; it++) curF[it] = nxtF[it];
    curG[0] = nxtG[0]; curG[1] = nxtG[1];
  }
}

// ---------------- deterministic stats reduce -> scale/shift ----------------
// partials layout: [(b*HH+y)][64]; block o sums slots o*2 (sum) and o*2+1 (sq)
__global__ void __launch_bounds__(512) k_stats(
    const float* __restrict__ partials,
    const float* __restrict__ g, const float* __restrict__ bb,
    float* __restrict__ bnp){
  __shared__ float acc[512];
  int o = blockIdx.x, t = threadIdx.x;
  int half = t >> 8, j = t & 255;
  float s = 0.f;
  for (int k=j; k<BATCH*HH; k+=256) s += partials[(size_t)k*64 + o*2 + half];
  acc[t] = s;
  __syncthreads();
  for (int w2=128; w2>0; w2>>=1){
    if (j < w2) acc[t] += acc[t+w2];
    __syncthreads();
  }
  if (t == 0){
    const float N = (float)BATCH * (float)(HH*HH);
    float mean = acc[0] / N;
    float var  = acc[256] / N - mean*mean;
    float iv = rsqrtf(var + 1e-5f);
    float scv = g[o]*iv;
    bnp[o]      = scv;
    bnp[CH + o] = bb[o] - mean*scv;
  }
}

// ------- final MFMA: BN(l3) + fc1 + relu + fc2, quadrant only --------------
__global__ void __launch_bounds__(256) k_final(
    const _Float16* __restrict__ tb, const float* __restrict__ bnp,
    const _Float16* __restrict__ W1h, const _Float16* __restrict__ W1l,
    const float* __restrict__ b1, const float* __restrict__ w2,
    const float* __restrict__ b2, float* __restrict__ out){
  __shared__ _Float16 Vf[128][40];      // pixel-major, 80B row stride
  int yq = blockIdx.x, b = blockIdx.y, t = threadIdx.x;
  int y = (SS-1) + yq;
  for (int i=t; i<CH*SS; i+=256){
    int c = i >> 7, xx = i & 127;
    float v = (float)tb[((size_t)(b*CH + c)*HH + y)*RST + (SS-1) + xx]
              * bnp[c] + bnp[CH+c];
    Vf[xx][c] = (_Float16)v;
  }
  __syncthreads();
  int w = t >> 6, lane = t & 63;
  int prow = lane & 15, koff = (lane >> 4)*8, col = lane & 15;
  f16x8 a0 = *(const f16x8*)&Vf[w*32 + prow][koff];
  f16x8 a1 = *(const f16x8*)&Vf[w*32 + 16 + prow][koff];
  float s0[4] = {0.f,0.f,0.f,0.f}, s1[4] = {0.f,0.f,0.f,0.f};
  #pragma unroll
  for (int nt=0; nt<8; nt++){
    f16x8 bh = *(const f16x8*)(W1h + ((size_t)nt*64 + lane)*8);
    f16x8 bl = *(const f16x8*)(W1l + ((size_t)nt*64 + lane)*8);
    f32x4 acc0 = {0.f,0.f,0.f,0.f}, acc1 = {0.f,0.f,0.f,0.f};
    acc0 = __builtin_amdgcn_mfma_f32_16x16x32_f16(a0, bh, acc0, 0,0,0);
    acc0 = __builtin_amdgcn_mfma_f32_16x16x32_f16(a0, bl, acc0, 0,0,0);
    acc1 = __builtin_amdgcn_mfma_f32_16x16x32_f16(a1, bh, acc1, 0,0,0);
    acc1 = __builtin_amdgcn_mfma_f32_16x16x32_f16(a1, bl, acc1, 0,0,0);
    float b1v = b1[nt*16 + col];
    float w2v = w2[nt*16 + col];
    #pragma unroll
    for (int q=0; q<4; q++){
      s0[q] += fmaxf(acc0[q] + b1v, 0.f)*w2v;
      s1[q] += fmaxf(acc1[q] + b1v, 0.f)*w2v;
    }
  }
  float o2b = b2[0];
  #pragma unroll
  for (int q=0; q<4; q++){
    float v0 = s0[q], v1 = s1[q];
    #pragma unroll
    for (int off=8; off>0; off>>=1){
      v0 += __shfl_xor(v0, off, 16);
      v1 += __shfl_xor(v1, off, 16);
    }
    if (col == (unsigned)q){           // one writer per pixel, deterministic
      int p0 = w*32 + (lane >> 4)*4 + q;
      int p1 = p0 + 16;
      float r0 = v0 + o2b, r1 = v1 + o2b;
      int ob = (b*DC)*SS*SS + yq*SS;
      #pragma unroll
      for (int cc=0; cc<DC; cc++){
        out[ob + cc*SS*SS + p0] = r0;
        out[ob + cc*SS*SS + p1] = r1;
      }
    }
  }
}

extern "C" void kernel_launch(void* const* d_in, const int* in_sizes, int n_in,
                              void* d_out, int out_size, void* d_ws, size_t ws_size,
                              hipStream_t stream) {
  (void)in_sizes; (void)n_in; (void)out_size; (void)ws_size;
  const float* x      = (const float*)d_in[0];
  const float* fc0_w  = (const float*)d_in[1];
  const float* fc0_b  = (const float*)d_in[2];
  const float* spec_w = (const float*)d_in[3];
  const float* conv_w = (const float*)d_in[4];
  const float* conv_b = (const float*)d_in[5];
  const float* bn_g   = (const float*)d_in[6];
  const float* bn_b   = (const float*)d_in[7];
  const float* fc1_w  = (const float*)d_in[8];
  const float* fc1_b  = (const float*)d_in[9];
  const float* fc2_w  = (const float*)d_in[10];
  const float* fc2_b  = (const float*)d_in[11];
  float* out = (float*)d_out;
  float* ws  = (float*)d_ws;

  // field: 16*32*255*256 f16 = 33,423,360 halves = 16,711,680 floats (~64 MiB)
  _Float16* field = (_Float16*)ws;
  float* Rbuf  = ws + 16711680;                        // NROWS*24 = 3,133,440
  float* Xf    = Rbuf + (size_t)NROWS*24;              // 294,912
  float* Yb    = Xf   + (size_t)BATCH*CH*KY24*M2*2;    // 294,912
  float* parts = Yb   + (size_t)BATCH*CH*KY24*M2*2;    // 261,120
  float* bnp   = parts + (size_t)64*BATCH*HH;          // 5 slots x 64
  _Float16* Whi = (_Float16*)(bnp + 5*64);             // 8192 halves each
  _Float16* Wlo = Whi + 2*8*64*8;
  _Float16* Th  = Wlo + 2*8*64*8;
  _Float16* Tl  = Th  + 16*64*8;
  _Float16* W1h = Tl  + 16*64*8;                       // 4096 halves each
  _Float16* W1l = W1h + 8*64*8;

  k_wgen<<<4, 256, 0, stream>>>(Whi, Wlo);
  k_tgen<<<4, 256, 0, stream>>>(Th, Tl);
  k_w1gen<<<2, 256, 0, stream>>>(fc1_w, W1h, W1l);
  k_fc0<<<dim3(HH, BATCH), 256, 0, stream>>>(x, fc0_w, fc0_b, field, bnp);

  const size_t wstride = (size_t)2*CH*CH*M1*M2*2;      // per-layer spec_w elems
  for (int l=0; l<4; l++){
    const float* bnin = bnp + (size_t)l*64;            // BN of layer l-1 (or id)
    int relu = (l >= 1);                               // ReLU after layers 0..2
    k_dftw <<<NROWS/64, 256, 0, stream>>>(field, Rbuf, Whi, Wlo, bnin, relu);
    k_dfth <<<BATCH*CH, 320, 0, stream>>>(Rbuf, Xf);
    k_mix  <<<dim3(M2, 2, BATCH), 384, 0, stream>>>(Xf, spec_w + (size_t)l*wstride, Yb);
    k_idfth<<<BATCH*CH, 256, 0, stream>>>(Yb, Rbuf);
    k_fuse <<<dim3(64, BATCH), 256, 0, stream>>>(field, Rbuf, conv_w + l*CH*CH,
                                                 conv_b + l*CH, field, parts,
                                                 Th, Tl, bnin, relu);
    k_stats<<<CH, 512, 0, stream>>>(parts, bn_g + l*CH, bn_b + l*CH,
                                    bnp + (size_t)(l+1)*64);
  }
  k_final<<<dim3(SS, BATCH), 256, 0, stream>>>(field, bnp + 4*64, W1h, W1l,
                                               fc1_b, fc2_w, fc2_b, out);
}

// Round 13
// 551.586 us; speedup vs baseline: 1.1427x; 1.1427x over previous
//
#include <hip/hip_runtime.h>

#define BATCH 16
#define CH 32
#define DC 3
#define SS 128
#define HH 255
#define RST 256                 // padded row stride (f16, 512B-aligned rows)
#define CST (HH*RST)            // channel stride in field
#define M1 12
#define M2 12
#define KY24 (2*M1)
#define NROWS (BATCH*CH*HH)
#define TWOPI_N 0.02463994238463573f   // 2*pi/255

typedef __attribute__((ext_vector_type(8))) _Float16 f16x8;
typedef __attribute__((ext_vector_type(4))) float f32x4;

// ------- mirror + fc0 lift, vectorized f16x8 stores (+ BN slot0 init) ------
// thread t: channel d = t>>3, group g = t&7; 4 iters of 8 px each.
__global__ void __launch_bounds__(256) k_fc0(
    const float* __restrict__ x, const float* __restrict__ w,
    const float* __restrict__ bias, _Float16* __restrict__ h,
    float* __restrict__ bnp0){
  int y = blockIdx.x, b = blockIdx.y, t = threadIdx.x;
  if (blockIdx.x == 0 && blockIdx.y == 0 && t < CH){
    bnp0[t] = 1.f; bnp0[CH+t] = 0.f;
  }
  int d = t >> 3, g = t & 7;
  int iy = (y >= SS-1) ? y - (SS-1) : (SS-1) - y;
  float w0 = w[d], w1 = w[CH+d], w2 = w[2*CH+d], bs = bias[d];
  const float* xp = x + (size_t)(b*DC)*SS*SS + iy*SS;
  size_t obase = ((size_t)(b*CH + d)*HH + y)*RST;
  #pragma unroll
  for (int i=0; i<4; i++){
    int x0 = i*64 + g*8;
    f16x8 pk;
    #pragma unroll
    for (int u=0; u<8; u++){
      int xx = x0 + u;
      float v = 0.f;
      if (xx < HH){
        int ix = (xx >= SS-1) ? xx - (SS-1) : (SS-1) - xx;
        float sgn = ((y >= SS-1) == (xx >= SS-1)) ? 1.f : -1.f;
        v = bs + sgn*(xp[ix]*w0 + xp[SS*SS+ix]*w1 + xp[2*SS*SS+ix]*w2);
      }
      pk[u] = (_Float16)v;
    }
    *(f16x8*)(h + obase + x0) = pk;
  }
}

// ------- all weight/twiddle tables in one kernel ---------------------------
// blocks 0-3: W (dftw), 4-7: T (fuse), 8-9: W1 (final)
__global__ void __launch_bounds__(256) k_tabs(
    const float* __restrict__ w1,
    _Float16* __restrict__ Whi, _Float16* __restrict__ Wlo,
    _Float16* __restrict__ Th,  _Float16* __restrict__ Tl,
    _Float16* __restrict__ W1h, _Float16* __restrict__ W1l){
  int bi = blockIdx.x;
  if (bi < 4){
    int t = bi*256 + threadIdx.x;          // t < 1024 = 2*8*64
    int ct = t >> 9, ks = (t >> 6) & 7, lane = t & 63;
    int col = ct*16 + (lane & 15);
    int kb = ks*32 + (lane >> 4)*8;
    for (int j=0; j<8; j++){
      int k = kb + j;
      float w = 0.f;
      if (k < 255 && col < 24){
        int m = col >> 1;
        float ang = TWOPI_N * (float)((k*m) % 255);
        w = (col & 1) ? -sinf(ang) : cosf(ang);
      }
      _Float16 hi = (_Float16)w;
      Whi[t*8+j] = hi;
      Wlo[t*8+j] = (_Float16)(w - (float)hi);
    }
  } else if (bi < 8){
    int t = (bi-4)*256 + threadIdx.x;      // t < 1024 = 16*64
    int ct = t >> 6, lane = t & 63;
    int xx = ct*16 + (lane & 15);
    int jbase = (lane >> 4)*8;
    for (int j=0; j<8; j++){
      int jg = jbase + j;
      float v = 0.f;
      if (xx < HH && jg <= 22){
        if (jg == 0) v = 1.f;
        else if (jg & 1){ int kx=(jg+1)>>1; v =  cosf(TWOPI_N*(float)((kx*xx)%255)); }
        else            { int kx= jg>>1;    v = -sinf(TWOPI_N*(float)((kx*xx)%255)); }
      }
      _Float16 hi = (_Float16)v;
      Th[t*8+j] = hi;
      Tl[t*8+j] = (_Float16)(v - (float)hi);
    }
  } else {
    int t = (bi-8)*256 + threadIdx.x;      // t < 512 = 8*64
    int nt = t >> 6, lane = t & 63;
    int col = nt*16 + (lane & 15);
    int kb = (lane >> 4)*8;
    for (int j=0; j<8; j++){
      float v = w1[(kb+j)*128 + col];
      _Float16 hi = (_Float16)v;
      W1h[t*8+j] = hi;
      W1l[t*8+j] = (_Float16)(v - (float)hi);
    }
  }
}

// ----- forward DFT along W via f16 MFMA (all data loads hoisted up front) --
__global__ void __launch_bounds__(256) k_dftw(
    const _Float16* __restrict__ h, float* __restrict__ R,
    const _Float16* __restrict__ Whi, const _Float16* __restrict__ Wlo,
    const float* __restrict__ bnp, int relu){
  int t = threadIdx.x;
  int wid = t >> 6, lane = t & 63;
  int r0 = blockIdx.x*64 + wid*16;
  int rowg = r0 + (lane & 15);
  int c = (rowg / HH) & (CH-1);
  _Float16 sch = (_Float16)bnp[c], shh = (_Float16)bnp[CH+c];
  f16x8 scv, shv;
  #pragma unroll
  for (int u=0; u<8; u++){ scv[u]=sch; shv[u]=shh; }
  const _Float16* rp = h + (size_t)rowg*RST;
  int koff = (lane >> 4)*8;
  f16x8 av[8];
  #pragma unroll
  for (int ks=0; ks<8; ks++)
    av[ks] = *(const f16x8*)(rp + ks*32 + koff);
  f32x4 acc0 = {0.f,0.f,0.f,0.f};
  f32x4 acc1 = {0.f,0.f,0.f,0.f};
  #pragma unroll
  for (int ks=0; ks<8; ks++){
    f16x8 a = av[ks]*scv + shv;             // packed f16 BN
    if (relu){
      #pragma unroll
      for (int u=0; u<8; u++) a[u] = (a[u] > (_Float16)0.f) ? a[u] : (_Float16)0.f;
    }
    f16x8 b0h = *(const f16x8*)(Whi + ((size_t)(0*8+ks)*64 + lane)*8);
    f16x8 b0l = *(const f16x8*)(Wlo + ((size_t)(0*8+ks)*64 + lane)*8);
    f16x8 b1h = *(const f16x8*)(Whi + ((size_t)(1*8+ks)*64 + lane)*8);
    f16x8 b1l = *(const f16x8*)(Wlo + ((size_t)(1*8+ks)*64 + lane)*8);
    acc0 = __builtin_amdgcn_mfma_f32_16x16x32_f16(a, b0h, acc0, 0,0,0);
    acc0 = __builtin_amdgcn_mfma_f32_16x16x32_f16(a, b0l, acc0, 0,0,0);
    acc1 = __builtin_amdgcn_mfma_f32_16x16x32_f16(a, b1h, acc1, 0,0,0);
    acc1 = __builtin_amdgcn_mfma_f32_16x16x32_f16(a, b1l, acc1, 0,0,0);
  }
  int colq = lane & 15;
  int rq = r0 + (lane >> 4)*4;
  #pragma unroll
  for (int q=0; q<4; q++)
    R[(size_t)(rq+q)*24 + colq] = acc0[q];
  if (colq < 8){
    #pragma unroll
    for (int q=0; q<4; q++)
      R[(size_t)(rq+q)*24 + 16 + colq] = acc1[q];
  }
}

// ---------------- forward DFT along H: R -> Xf[bc][ky24][kx12], *1/255 -----
__global__ void __launch_bounds__(320) k_dfth(
    const float* __restrict__ R, float* __restrict__ Xf){
  __shared__ float lr[HH][M2][2];
  int t = threadIdx.x, bc = blockIdx.x;
  const float4* src = (const float4*)(R + bc*(HH*M2*2));
  for (int i=t; i<(HH*M2*2)/4; i+=320) ((float4*)lr)[i] = src[i];
  __syncthreads();
  if (t < KY24*M2){
    int ky = t / M2, kx = t - (t/M2)*M2;
    int freq = (ky < M1) ? ky : (HH - KY24 + ky);  // 0..11 or 243..254
    float ang = TWOPI_N * (float)freq;
    float c1 = cosf(ang), s1 = sinf(ang);
    float cr=1.f, sr=0.f, ar=0.f, ai=0.f;
    for (int y=0; y<HH; y++){
      float rr = lr[y][kx][0], ri = lr[y][kx][1];
      ar += rr*cr + ri*sr;   // * e^{-i theta}
      ai += ri*cr - rr*sr;
      float cn = cr*c1 - sr*s1;
      sr = sr*c1 + cr*s1;
      cr = cn;
    }
    const float inv = 1.0f/255.0f;
    int o = (bc*KY24 + ky)*(M2*2) + kx*2;
    Xf[o]   = ar*inv;
    Xf[o+1] = ai*inv;
  }
}

// ------- fused channel-mix + inverse along H: Xf -> G[bo][y][kx] -----------
// per (b,o) block: phase A mixes 288 modes into LDS; phase B = inverse-H.
__global__ void __launch_bounds__(256) k_specmix(
    const float* __restrict__ Xf, const float* __restrict__ w,
    float* __restrict__ G){
  __shared__ float ly[KY24][M2][2];
  int o = blockIdx.x, b = blockIdx.y, t = threadIdx.x;
  for (int m = t; m < KY24*M2; m += 256){
    int ky = m / M2, kx = m - (m/M2)*M2;
    int blk = (ky < M1) ? 1 : 0;  blk = (ky < M1) ? 0 : 1;
    int m1 = ky - blk*M1;
    const float* wp = w + (size_t)blk*(CH*CH*M1*M2*2)
                        + (size_t)o*(M1*M2*2) + m1*(M2*2) + kx*2;
    const float* xp = Xf + ((size_t)(b*CH)*KY24 + ky)*(M2*2) + kx*2;
    float ar=0.f, ai=0.f;
    for (int i=0;i<CH;i++){
      float xr = xp[0], xi = xp[1];
      float wr = wp[0], wi = wp[1];
      ar += xr*wr - xi*wi;
      ai += xr*wi + xi*wr;
      xp += KY24*M2*2;
      wp += CH*M1*M2*2;
    }
    ly[ky][kx][0] = ar;
    ly[ky][kx][1] = ai;
  }
  __syncthreads();
  const float inv = 1.0f/255.0f;
  size_t bo = (size_t)b*CH + o;
  for (int p=t; p<HH*M2; p+=256){
    int y = p/M2, kx = p - (p/M2)*M2;
    float ang = TWOPI_N * (float)y;
    float c1 = cosf(ang), s1 = sinf(ang);
    float ar = ly[0][kx][0], ai = ly[0][kx][1];
    float c = c1, s = s1;
    #pragma unroll
    for (int k=1; k<=11; k++){
      float yr = ly[k][kx][0],     yi = ly[k][kx][1];
      ar += yr*c - yi*s;                 // * T_k
      ai += yr*s + yi*c;
      float zr = ly[24-k][kx][0],  zi = ly[24-k][kx][1];
      ar += zr*c + zi*s;                 // * conj(T_k)
      ai += zi*c - zr*s;
      float cn = c*c1 - s*s1;
      s = s*c1 + c*s1;
      c = cn;
    }
    {
      float zr = ly[12][kx][0], zi = ly[12][kx][1];   // freq -12: conj(T_12)
      ar += zr*c + zi*s;
      ai += zi*c - zr*s;
    }
    float f = (kx==0) ? inv : 2.0f*inv;
    size_t og = (bo*HH + y)*(M2*2) + kx*2;
    G[og]   = ar*f;
    G[og+1] = ai*f;
  }
}

// ------- fused MFMA (1 row/block): conv + inv-W + partials -----------------
__global__ void __launch_bounds__(256) k_fuse(
    const _Float16* __restrict__ h, const float* __restrict__ G,
    const float* __restrict__ cw, const float* __restrict__ cb,
    _Float16* __restrict__ tout, float* __restrict__ partials,
    const _Float16* __restrict__ Th, const _Float16* __restrict__ Tl,
    const float* __restrict__ bnp, int relu){
  __shared__ _Float16 buf[8448];   // Bf: (ct*65+lane)*8+j ; Of: o*264+xx
  __shared__ float red[CH][4][2];
  int t = threadIdx.x;
  int y = blockIdx.x, b = blockIdx.y;
  size_t hbase = (size_t)(b*CH*HH + y)*RST;
  // --- hoisted staging loads (4 per thread, issued before anything) ---
  int cS = t >> 5, xg = t & 31;
  f16x8 ld[4];
  #pragma unroll
  for (int it=0; it<4; it++)
    ld[it] = *(const f16x8*)(h + hbase + (size_t)(it*8 + cS)*CST + xg*8);
  // --- A fragments (independent loads; overlap staging latency) ---
  int w = t >> 6, lane = t & 63;
  int arow = lane & 15, koff = (lane >> 4)*8;
  f16x8 a0h[2], a0l[2], a1[2];
  #pragma unroll
  for (int rt=0; rt<2; rt++){
    int o = rt*16 + arow;
    #pragma unroll
    for (int j=0; j<8; j++){
      float v = cw[o*CH + koff + j];
      _Float16 hi = (_Float16)v;
      a0h[rt][j] = hi;
      a0l[rt][j] = (_Float16)(v - (float)hi);
    }
    const float* gp = G + ((size_t)(b*CH+o)*HH + y)*24;
    #pragma unroll
    for (int j=0; j<8; j++){
      int jg = koff + j;                 // jg>=23: T rows are zero -> don't care
      float v = (jg==0) ? gp[0] : gp[jg+1];
      a1[rt][j] = (_Float16)v;
    }
  }
  // --- BN + scatter to LDS fragments ---
  #pragma unroll
  for (int it=0; it<4; it++){
    int c = it*8 + cS;
    _Float16 sc_ = (_Float16)bnp[c], sh_ = (_Float16)bnp[CH+c];
    f16x8 scv, shv;
    #pragma unroll
    for (int u=0; u<8; u++){ scv[u]=sc_; shv[u]=sh_; }
    f16x8 z = ld[it]*scv + shv;
    if (relu){
      #pragma unroll
      for (int u=0; u<8; u++) z[u] = (z[u] > (_Float16)0.f) ? z[u] : (_Float16)0.f;
    }
    int base = ((xg>>1)*65 + ((xg&1)*8) + ((c>>3)<<4))*8 + (c&7);
    #pragma unroll
    for (int u=0; u<8; u++) buf[base + u*8] = z[u];
  }
  __syncthreads();
  // --- MFMA: each wave owns 4 col-tiles (64 xx), all 32 output rows ---
  f32x4 acc[2][4];
  #pragma unroll
  for (int rt=0; rt<2; rt++)
    #pragma unroll
    for (int cl=0; cl<4; cl++) acc[rt][cl] = (f32x4){0.f,0.f,0.f,0.f};
  #pragma unroll
  for (int cl=0; cl<4; cl++){
    int ct = w*4 + cl;
    f16x8 bd = *(const f16x8*)(buf + ((size_t)ct*65 + lane)*8);
    f16x8 th = *(const f16x8*)(Th + ((size_t)ct*64 + lane)*8);
    f16x8 tl = *(const f16x8*)(Tl + ((size_t)ct*64 + lane)*8);
    #pragma unroll
    for (int rt=0; rt<2; rt++){
      acc[rt][cl] = __builtin_amdgcn_mfma_f32_16x16x32_f16(a0h[rt], bd, acc[rt][cl], 0,0,0);
      acc[rt][cl] = __builtin_amdgcn_mfma_f32_16x16x32_f16(a0l[rt], bd, acc[rt][cl], 0,0,0);
      acc[rt][cl] = __builtin_amdgcn_mfma_f32_16x16x32_f16(a1[rt], th, acc[rt][cl], 0,0,0);
      acc[rt][cl] = __builtin_amdgcn_mfma_f32_16x16x32_f16(a1[rt], tl, acc[rt][cl], 0,0,0);
    }
  }
  // --- BN partial sums from registers (exclude pad col) ---
  #pragma unroll
  for (int rt=0; rt<2; rt++)
    #pragma unroll
    for (int q=0; q<4; q++){
      float v1 = 0.f, v2 = 0.f;
      #pragma unroll
      for (int cl=0; cl<4; cl++){
        int xxo = (w*4 + cl)*16 + (lane & 15);
        int o = rt*16 + (lane >> 4)*4 + q;
        float v = acc[rt][cl][q] + cb[o];
        float vv = (xxo < HH) ? v : 0.f;
        v1 += vv; v2 += vv*vv;
      }
      #pragma unroll
      for (int off=8; off>0; off>>=1){
        v1 += __shfl_xor(v1, off, 16);
        v2 += __shfl_xor(v2, off, 16);
      }
      if ((lane & 15) == 0){
        int o = rt*16 + (lane >> 4)*4 + q;
        red[o][w][0] = v1;
        red[o][w][1] = v2;
      }
    }
  __syncthreads();      // all Bf reads done -> safe to overwrite buf as Of
  #pragma unroll
  for (int rt=0; rt<2; rt++)
    #pragma unroll
    for (int cl=0; cl<4; cl++){
      int xxo = (w*4 + cl)*16 + (lane & 15);
      #pragma unroll
      for (int q=0; q<4; q++){
        int o = rt*16 + (lane >> 4)*4 + q;     // C/D layout (m89)
        buf[o*264 + xxo] = (_Float16)(acc[rt][cl][q] + cb[o]);
      }
    }
  __syncthreads();
  // --- coalesced f16x8 row stores (pad col written too; harmless) ---
  {
    int o = t >> 3, xb = (t & 7)*32;
    #pragma unroll
    for (int v4=0; v4<4; v4++){
      f16x8 vv = *(const f16x8*)(buf + o*264 + xb + v4*8);
      *(f16x8*)(tout + hbase + (size_t)o*CST + xb + v4*8) = vv;
    }
  }
  // --- contiguous 256B partials write per block ---
  if (t < CH*2){
    int oo = t >> 1, st = t & 1;
    float s = red[oo][0][st] + red[oo][1][st] + red[oo][2][st] + red[oo][3][st];
    partials[((size_t)b*HH + y)*64 + t] = s;
  }
}

// ---------------- deterministic stats reduce -> scale/shift ----------------
// partials layout: [(b*HH+y)][64]; block o sums slots o*2 (sum) and o*2+1 (sq)
__global__ void __launch_bounds__(512) k_stats(
    const float* __restrict__ partials,
    const float* __restrict__ g, const float* __restrict__ bb,
    float* __restrict__ bnp){
  __shared__ float acc[512];
  int o = blockIdx.x, t = threadIdx.x;
  int half = t >> 8, j = t & 255;
  float s = 0.f;
  for (int k=j; k<BATCH*HH; k+=256) s += partials[(size_t)k*64 + o*2 + half];
  acc[t] = s;
  __syncthreads();
  for (int w2=128; w2>0; w2>>=1){
    if (j < w2) acc[t] += acc[t+w2];
    __syncthreads();
  }
  if (t == 0){
    const float N = (float)BATCH * (float)(HH*HH);
    float mean = acc[0] / N;
    float var  = acc[256] / N - mean*mean;
    float iv = rsqrtf(var + 1e-5f);
    float scv = g[o]*iv;
    bnp[o]      = scv;
    bnp[CH + o] = bb[o] - mean*scv;
  }
}

// ------- final MFMA: BN(l3) + fc1 + relu + fc2, quadrant only --------------
__global__ void __launch_bounds__(256) k_final(
    const _Float16* __restrict__ tb, const float* __restrict__ bnp,
    const _Float16* __restrict__ W1h, const _Float16* __restrict__ W1l,
    const float* __restrict__ b1, const float* __restrict__ w2,
    const float* __restrict__ b2, float* __restrict__ out){
  __shared__ _Float16 Vf[128][40];      // pixel-major, 80B row stride
  int yq = blockIdx.x, b = blockIdx.y, t = threadIdx.x;
  int y = (SS-1) + yq;
  for (int i=t; i<CH*SS; i+=256){
    int c = i >> 7, xx = i & 127;
    float v = (float)tb[((size_t)(b*CH + c)*HH + y)*RST + (SS-1) + xx]
              * bnp[c] + bnp[CH+c];
    Vf[xx][c] = (_Float16)v;
  }
  __syncthreads();
  int w = t >> 6, lane = t & 63;
  int prow = lane & 15, koff = (lane >> 4)*8, col = lane & 15;
  f16x8 a0 = *(const f16x8*)&Vf[w*32 + prow][koff];
  f16x8 a1 = *(const f16x8*)&Vf[w*32 + 16 + prow][koff];
  float s0[4] = {0.f,0.f,0.f,0.f}, s1[4] = {0.f,0.f,0.f,0.f};
  #pragma unroll
  for (int nt=0; nt<8; nt++){
    f16x8 bh = *(const f16x8*)(W1h + ((size_t)nt*64 + lane)*8);
    f16x8 bl = *(const f16x8*)(W1l + ((size_t)nt*64 + lane)*8);
    f32x4 acc0 = {0.f,0.f,0.f,0.f}, acc1 = {0.f,0.f,0.f,0.f};
    acc0 = __builtin_amdgcn_mfma_f32_16x16x32_f16(a0, bh, acc0, 0,0,0);
    acc0 = __builtin_amdgcn_mfma_f32_16x16x32_f16(a0, bl, acc0, 0,0,0);
    acc1 = __builtin_amdgcn_mfma_f32_16x16x32_f16(a1, bh, acc1, 0,0,0);
    acc1 = __builtin_amdgcn_mfma_f32_16x16x32_f16(a1, bl, acc1, 0,0,0);
    float b1v = b1[nt*16 + col];
    float w2v = w2[nt*16 + col];
    #pragma unroll
    for (int q=0; q<4; q++){
      s0[q] += fmaxf(acc0[q] + b1v, 0.f)*w2v;
      s1[q] += fmaxf(acc1[q] + b1v, 0.f)*w2v;
    }
  }
  float o2b = b2[0];
  #pragma unroll
  for (int q=0; q<4; q++){
    float v0 = s0[q], v1 = s1[q];
    #pragma unroll
    for (int off=8; off>0; off>>=1){
      v0 += __shfl_xor(v0, off, 16);
      v1 += __shfl_xor(v1, off, 16);
    }
    if (col == (unsigned)q){           // one writer per pixel, deterministic
      int p0 = w*32 + (lane >> 4)*4 + q;
      int p1 = p0 + 16;
      float r0 = v0 + o2b, r1 = v1 + o2b;
      int ob = (b*DC)*SS*SS + yq*SS;
      #pragma unroll
      for (int cc=0; cc<DC; cc++){
        out[ob + cc*SS*SS + p0] = r0;
        out[ob + cc*SS*SS + p1] = r1;
      }
    }
  }
}

extern "C" void kernel_launch(void* const* d_in, const int* in_sizes, int n_in,
                              void* d_out, int out_size, void* d_ws, size_t ws_size,
                              hipStream_t stream) {
  (void)in_sizes; (void)n_in; (void)out_size; (void)ws_size;
  const float* x      = (const float*)d_in[0];
  const float* fc0_w  = (const float*)d_in[1];
  const float* fc0_b  = (const float*)d_in[2];
  const float* spec_w = (const float*)d_in[3];
  const float* conv_w = (const float*)d_in[4];
  const float* conv_b = (const float*)d_in[5];
  const float* bn_g   = (const float*)d_in[6];
  const float* bn_b   = (const float*)d_in[7];
  const float* fc1_w  = (const float*)d_in[8];
  const float* fc1_b  = (const float*)d_in[9];
  const float* fc2_w  = (const float*)d_in[10];
  const float* fc2_b  = (const float*)d_in[11];
  float* out = (float*)d_out;
  float* ws  = (float*)d_ws;

  // field: 16*32*255*256 f16 = 33,423,360 halves = 16,711,680 floats (~64 MiB)
  _Float16* field = (_Float16*)ws;
  float* Rbuf  = ws + 16711680;                        // NROWS*24 = 3,133,440
  float* Xf    = Rbuf + (size_t)NROWS*24;              // 294,912
  float* parts = Xf   + (size_t)BATCH*CH*KY24*M2*2;    // 261,120
  float* bnp   = parts + (size_t)64*BATCH*HH;          // 5 slots x 64
  _Float16* Whi = (_Float16*)(bnp + 5*64);             // 8192 halves each
  _Float16* Wlo = Whi + 2*8*64*8;
  _Float16* Th  = Wlo + 2*8*64*8;
  _Float16* Tl  = Th  + 16*64*8;
  _Float16* W1h = Tl  + 16*64*8;                       // 4096 halves each
  _Float16* W1l = W1h + 8*64*8;

  k_tabs<<<10, 256, 0, stream>>>(fc1_w, Whi, Wlo, Th, Tl, W1h, W1l);
  k_fc0<<<dim3(HH, BATCH), 256, 0, stream>>>(x, fc0_w, fc0_b, field, bnp);

  const size_t wstride = (size_t)2*CH*CH*M1*M2*2;      // per-layer spec_w elems
  for (int l=0; l<4; l++){
    const float* bnin = bnp + (size_t)l*64;            // BN of layer l-1 (or id)
    int relu = (l >= 1);                               // ReLU after layers 0..2
    k_dftw <<<NROWS/64, 256, 0, stream>>>(field, Rbuf, Whi, Wlo, bnin, relu);
    k_dfth <<<BATCH*CH, 320, 0, stream>>>(Rbuf, Xf);
    k_specmix<<<dim3(CH, BATCH), 256, 0, stream>>>(Xf, spec_w + (size_t)l*wstride, Rbuf);
    k_fuse <<<dim3(HH, BATCH), 256, 0, stream>>>(field, Rbuf, conv_w + l*CH*CH,
                                                 conv_b + l*CH, field, parts,
                                                 Th, Tl, bnin, relu);
    k_stats<<<CH, 512, 0, stream>>>(parts, bn_g + l*CH, bn_b + l*CH,
                                    bnp + (size_t)(l+1)*64);
  }
  k_final<<<dim3(SS, BATCH), 256, 0, stream>>>(field, bnp + 4*64, W1h, W1l,
                                               fc1_b, fc2_w, fc2_b, out);
}

// Round 14
// 534.452 us; speedup vs baseline: 1.1794x; 1.0321x over previous
//
#include <hip/hip_runtime.h>

#define BATCH 16
#define CH 32
#define DC 3
#define SS 128
#define HH 255
#define RST 256                 // padded row stride (f16, 512B-aligned rows)
#define CST (HH*RST)            // channel stride in field
#define M1 12
#define M2 12
#define KY24 (2*M1)
#define NROWS (BATCH*CH*HH)
#define TWOPI_N 0.02463994238463573f   // 2*pi/255

typedef __attribute__((ext_vector_type(8))) _Float16 f16x8;
typedef __attribute__((ext_vector_type(4))) float f32x4;

// ------- mirror + fc0 lift, vectorized f16x8 stores (+ BN slot0 init) ------
__global__ void __launch_bounds__(256) k_fc0(
    const float* __restrict__ x, const float* __restrict__ w,
    const float* __restrict__ bias, _Float16* __restrict__ h,
    float* __restrict__ bnp0){
  int y = blockIdx.x, b = blockIdx.y, t = threadIdx.x;
  if (blockIdx.x == 0 && blockIdx.y == 0 && t < CH){
    bnp0[t] = 1.f; bnp0[CH+t] = 0.f;
  }
  int d = t >> 3, g = t & 7;
  int iy = (y >= SS-1) ? y - (SS-1) : (SS-1) - y;
  float w0 = w[d], w1 = w[CH+d], w2 = w[2*CH+d], bs = bias[d];
  const float* xp = x + (size_t)(b*DC)*SS*SS + iy*SS;
  size_t obase = ((size_t)(b*CH + d)*HH + y)*RST;
  #pragma unroll
  for (int i=0; i<4; i++){
    int x0 = i*64 + g*8;
    f16x8 pk;
    #pragma unroll
    for (int u=0; u<8; u++){
      int xx = x0 + u;
      float v = 0.f;
      if (xx < HH){
        int ix = (xx >= SS-1) ? xx - (SS-1) : (SS-1) - xx;
        float sgn = ((y >= SS-1) == (xx >= SS-1)) ? 1.f : -1.f;
        v = bs + sgn*(xp[ix]*w0 + xp[SS*SS+ix]*w1 + xp[2*SS*SS+ix]*w2);
      }
      pk[u] = (_Float16)v;
    }
    *(f16x8*)(h + obase + x0) = pk;
  }
}

// ------- all weight/twiddle tables in one kernel ---------------------------
__global__ void __launch_bounds__(256) k_tabs(
    const float* __restrict__ w1,
    _Float16* __restrict__ Whi, _Float16* __restrict__ Wlo,
    _Float16* __restrict__ Th,  _Float16* __restrict__ Tl,
    _Float16* __restrict__ W1h, _Float16* __restrict__ W1l){
  int bi = blockIdx.x;
  if (bi < 4){
    int t = bi*256 + threadIdx.x;          // t < 1024 = 2*8*64
    int ct = t >> 9, ks = (t >> 6) & 7, lane = t & 63;
    int col = ct*16 + (lane & 15);
    int kb = ks*32 + (lane >> 4)*8;
    for (int j=0; j<8; j++){
      int k = kb + j;
      float w = 0.f;
      if (k < 255 && col < 24){
        int m = col >> 1;
        float ang = TWOPI_N * (float)((k*m) % 255);
        w = (col & 1) ? -sinf(ang) : cosf(ang);
      }
      _Float16 hi = (_Float16)w;
      Whi[t*8+j] = hi;
      Wlo[t*8+j] = (_Float16)(w - (float)hi);
    }
  } else if (bi < 8){
    int t = (bi-4)*256 + threadIdx.x;      // t < 1024 = 16*64
    int ct = t >> 6, lane = t & 63;
    int xx = ct*16 + (lane & 15);
    int jbase = (lane >> 4)*8;
    for (int j=0; j<8; j++){
      int jg = jbase + j;
      float v = 0.f;
      if (xx < HH && jg <= 22){
        if (jg == 0) v = 1.f;
        else if (jg & 1){ int kx=(jg+1)>>1; v =  cosf(TWOPI_N*(float)((kx*xx)%255)); }
        else            { int kx= jg>>1;    v = -sinf(TWOPI_N*(float)((kx*xx)%255)); }
      }
      _Float16 hi = (_Float16)v;
      Th[t*8+j] = hi;
      Tl[t*8+j] = (_Float16)(v - (float)hi);
    }
  } else {
    int t = (bi-8)*256 + threadIdx.x;      // t < 512 = 8*64
    int nt = t >> 6, lane = t & 63;
    int col = nt*16 + (lane & 15);
    int kb = (lane >> 4)*8;
    for (int j=0; j<8; j++){
      float v = w1[(kb+j)*128 + col];
      _Float16 hi = (_Float16)v;
      W1h[t*8+j] = hi;
      W1l[t*8+j] = (_Float16)(v - (float)hi);
    }
  }
}

// ----- fused forward DFT (W via MFMA, then H via recurrence) ---------------
// one block per (b,c); R never leaves LDS.
__global__ void __launch_bounds__(256) k_fwd(
    const _Float16* __restrict__ h, float* __restrict__ Xf,
    const _Float16* __restrict__ Whi, const _Float16* __restrict__ Wlo,
    const float* __restrict__ bnp, int relu){
  __shared__ float lr[HH][26];           // [y][kx*2 + re/im], 26.5 KB
  int t = threadIdx.x, bc = blockIdx.x;
  int wid = t >> 6, lane = t & 63;
  int c = bc & (CH-1);
  _Float16 sch = (_Float16)bnp[c], shh = (_Float16)bnp[CH+c];  // block-uniform
  f16x8 scv, shv;
  #pragma unroll
  for (int u=0; u<8; u++){ scv[u]=sch; shv[u]=shh; }
  const _Float16* base = h + (size_t)bc*CST;
  int koff = (lane >> 4)*8;
  #pragma unroll
  for (int it=0; it<4; it++){
    int y0 = it*64 + wid*16;
    int yr = y0 + (lane & 15);
    int ycl = (yr < HH) ? yr : HH-1;     // clamp pad row (output discarded)
    const _Float16* rp = base + (size_t)ycl*RST;
    f16x8 av[8];
    #pragma unroll
    for (int ks=0; ks<8; ks++)
      av[ks] = *(const f16x8*)(rp + ks*32 + koff);
    f32x4 acc0 = {0.f,0.f,0.f,0.f};
    f32x4 acc1 = {0.f,0.f,0.f,0.f};
    #pragma unroll
    for (int ks=0; ks<8; ks++){
      f16x8 a = av[ks]*scv + shv;
      if (relu){
        #pragma unroll
        for (int u=0; u<8; u++) a[u] = (a[u] > (_Float16)0.f) ? a[u] : (_Float16)0.f;
      }
      f16x8 b0h = *(const f16x8*)(Whi + ((size_t)(0*8+ks)*64 + lane)*8);
      f16x8 b0l = *(const f16x8*)(Wlo + ((size_t)(0*8+ks)*64 + lane)*8);
      f16x8 b1h = *(const f16x8*)(Whi + ((size_t)(1*8+ks)*64 + lane)*8);
      f16x8 b1l = *(const f16x8*)(Wlo + ((size_t)(1*8+ks)*64 + lane)*8);
      acc0 = __builtin_amdgcn_mfma_f32_16x16x32_f16(a, b0h, acc0, 0,0,0);
      acc0 = __builtin_amdgcn_mfma_f32_16x16x32_f16(a, b0l, acc0, 0,0,0);
      acc1 = __builtin_amdgcn_mfma_f32_16x16x32_f16(a, b1h, acc1, 0,0,0);
      acc1 = __builtin_amdgcn_mfma_f32_16x16x32_f16(a, b1l, acc1, 0,0,0);
    }
    int colq = lane & 15;
    int rq = y0 + (lane >> 4)*4;
    #pragma unroll
    for (int q=0; q<4; q++)
      if (rq+q < HH) lr[rq+q][colq] = acc0[q];
    if (colq < 8){
      #pragma unroll
      for (int q=0; q<4; q++)
        if (rq+q < HH) lr[rq+q][16+colq] = acc1[q];
    }
  }
  __syncthreads();
  // phase 2: column DFT, 288 items over 256 threads
  for (int p = t; p < KY24*M2; p += 256){
    int ky = p / M2, kx = p - (p/M2)*M2;
    int freq = (ky < M1) ? ky : (HH - KY24 + ky);  // 0..11 or 243..254
    float ang = TWOPI_N * (float)freq;
    float c1 = cosf(ang), s1 = sinf(ang);
    float cr=1.f, sr=0.f, ar=0.f, ai=0.f;
    for (int y=0; y<HH; y++){
      float rr = lr[y][kx*2], ri = lr[y][kx*2+1];
      ar += rr*cr + ri*sr;   // * e^{-i theta}
      ai += ri*cr - rr*sr;
      float cn = cr*c1 - sr*s1;
      sr = sr*c1 + cr*s1;
      cr = cn;
    }
    const float inv = 1.0f/255.0f;
    int o = (bc*KY24 + ky)*(M2*2) + kx*2;
    Xf[o]   = ar*inv;
    Xf[o+1] = ai*inv;
  }
}

// ------- fused channel-mix + inverse along H: Xf -> G[bo][y][kx] -----------
__global__ void __launch_bounds__(256) k_specmix(
    const float* __restrict__ Xf, const float* __restrict__ w,
    float* __restrict__ G){
  __shared__ float ly[KY24][M2][2];
  int o = blockIdx.x, b = blockIdx.y, t = threadIdx.x;
  for (int m = t; m < KY24*M2; m += 256){
    int ky = m / M2, kx = m - (m/M2)*M2;
    int blk = (ky < M1) ? 0 : 1;
    int m1 = ky - blk*M1;
    const float* wp = w + (size_t)blk*(CH*CH*M1*M2*2)
                        + (size_t)o*(M1*M2*2) + m1*(M2*2) + kx*2;
    const float* xp = Xf + ((size_t)(b*CH)*KY24 + ky)*(M2*2) + kx*2;
    float ar=0.f, ai=0.f;
    for (int i=0;i<CH;i++){
      float xr = xp[0], xi = xp[1];
      float wr = wp[0], wi = wp[1];
      ar += xr*wr - xi*wi;
      ai += xr*wi + xi*wr;
      xp += KY24*M2*2;
      wp += CH*M1*M2*2;
    }
    ly[ky][kx][0] = ar;
    ly[ky][kx][1] = ai;
  }
  __syncthreads();
  const float inv = 1.0f/255.0f;
  size_t bo = (size_t)b*CH + o;
  for (int p=t; p<HH*M2; p+=256){
    int y = p/M2, kx = p - (p/M2)*M2;
    float ang = TWOPI_N * (float)y;
    float c1 = cosf(ang), s1 = sinf(ang);
    float ar = ly[0][kx][0], ai = ly[0][kx][1];
    float c = c1, s = s1;
    #pragma unroll
    for (int k=1; k<=11; k++){
      float yr = ly[k][kx][0],     yi = ly[k][kx][1];
      ar += yr*c - yi*s;                 // * T_k
      ai += yr*s + yi*c;
      float zr = ly[24-k][kx][0],  zi = ly[24-k][kx][1];
      ar += zr*c + zi*s;                 // * conj(T_k)
      ai += zi*c - zr*s;
      float cn = c*c1 - s*s1;
      s = s*c1 + c*s1;
      c = cn;
    }
    {
      float zr = ly[12][kx][0], zi = ly[12][kx][1];   // freq -12: conj(T_12)
      ar += zr*c + zi*s;
      ai += zi*c - zr*s;
    }
    float f = (kx==0) ? inv : 2.0f*inv;
    size_t og = (bo*HH + y)*(M2*2) + kx*2;
    G[og]   = ar*f;
    G[og+1] = ai*f;
  }
}

// ------- fused MFMA (1 row/block): conv + inv-W + partials -----------------
__global__ void __launch_bounds__(256) k_fuse(
    const _Float16* __restrict__ h, const float* __restrict__ G,
    const float* __restrict__ cw, const float* __restrict__ cb,
    _Float16* __restrict__ tout, float* __restrict__ partials,
    const _Float16* __restrict__ Th, const _Float16* __restrict__ Tl,
    const float* __restrict__ bnp, int relu){
  __shared__ _Float16 buf[8448];   // Bf: (ct*65+lane)*8+j ; Of: o*264+xx
  __shared__ float red[CH][4][2];
  int t = threadIdx.x;
  int y = blockIdx.x, b = blockIdx.y;
  size_t hbase = (size_t)(b*CH*HH + y)*RST;
  int cS = t >> 5, xg = t & 31;
  f16x8 ld[4];
  #pragma unroll
  for (int it=0; it<4; it++)
    ld[it] = *(const f16x8*)(h + hbase + (size_t)(it*8 + cS)*CST + xg*8);
  int w = t >> 6, lane = t & 63;
  int arow = lane & 15, koff = (lane >> 4)*8;
  f16x8 a0h[2], a0l[2], a1[2];
  #pragma unroll
  for (int rt=0; rt<2; rt++){
    int o = rt*16 + arow;
    #pragma unroll
    for (int j=0; j<8; j++){
      float v = cw[o*CH + koff + j];
      _Float16 hi = (_Float16)v;
      a0h[rt][j] = hi;
      a0l[rt][j] = (_Float16)(v - (float)hi);
    }
    const float* gp = G + ((size_t)(b*CH+o)*HH + y)*24;
    #pragma unroll
    for (int j=0; j<8; j++){
      int jg = koff + j;                 // jg>=23: T rows are zero -> don't care
      float v = (jg==0) ? gp[0] : gp[jg+1];
      a1[rt][j] = (_Float16)v;
    }
  }
  #pragma unroll
  for (int it=0; it<4; it++){
    int c = it*8 + cS;
    _Float16 sc_ = (_Float16)bnp[c], sh_ = (_Float16)bnp[CH+c];
    f16x8 scv, shv;
    #pragma unroll
    for (int u=0; u<8; u++){ scv[u]=sc_; shv[u]=sh_; }
    f16x8 z = ld[it]*scv + shv;
    if (relu){
      #pragma unroll
      for (int u=0; u<8; u++) z[u] = (z[u] > (_Float16)0.f) ? z[u] : (_Float16)0.f;
    }
    int base = ((xg>>1)*65 + ((xg&1)*8) + ((c>>3)<<4))*8 + (c&7);
    #pragma unroll
    for (int u=0; u<8; u++) buf[base + u*8] = z[u];
  }
  __syncthreads();
  f32x4 acc[2][4];
  #pragma unroll
  for (int rt=0; rt<2; rt++)
    #pragma unroll
    for (int cl=0; cl<4; cl++) acc[rt][cl] = (f32x4){0.f,0.f,0.f,0.f};
  #pragma unroll
  for (int cl=0; cl<4; cl++){
    int ct = w*4 + cl;
    f16x8 bd = *(const f16x8*)(buf + ((size_t)ct*65 + lane)*8);
    f16x8 th = *(const f16x8*)(Th + ((size_t)ct*64 + lane)*8);
    f16x8 tl = *(const f16x8*)(Tl + ((size_t)ct*64 + lane)*8);
    #pragma unroll
    for (int rt=0; rt<2; rt++){
      acc[rt][cl] = __builtin_amdgcn_mfma_f32_16x16x32_f16(a0h[rt], bd, acc[rt][cl], 0,0,0);
      acc[rt][cl] = __builtin_amdgcn_mfma_f32_16x16x32_f16(a0l[rt], bd, acc[rt][cl], 0,0,0);
      acc[rt][cl] = __builtin_amdgcn_mfma_f32_16x16x32_f16(a1[rt], th, acc[rt][cl], 0,0,0);
      acc[rt][cl] = __builtin_amdgcn_mfma_f32_16x16x32_f16(a1[rt], tl, acc[rt][cl], 0,0,0);
    }
  }
  #pragma unroll
  for (int rt=0; rt<2; rt++)
    #pragma unroll
    for (int q=0; q<4; q++){
      float v1 = 0.f, v2 = 0.f;
      #pragma unroll
      for (int cl=0; cl<4; cl++){
        int xxo = (w*4 + cl)*16 + (lane & 15);
        int o = rt*16 + (lane >> 4)*4 + q;
        float v = acc[rt][cl][q] + cb[o];
        float vv = (xxo < HH) ? v : 0.f;
        v1 += vv; v2 += vv*vv;
      }
      #pragma unroll
      for (int off=8; off>0; off>>=1){
        v1 += __shfl_xor(v1, off, 16);
        v2 += __shfl_xor(v2, off, 16);
      }
      if ((lane & 15) == 0){
        int o = rt*16 + (lane >> 4)*4 + q;
        red[o][w][0] = v1;
        red[o][w][1] = v2;
      }
    }
  __syncthreads();      // all Bf reads done -> safe to overwrite buf as Of
  #pragma unroll
  for (int rt=0; rt<2; rt++)
    #pragma unroll
    for (int cl=0; cl<4; cl++){
      int xxo = (w*4 + cl)*16 + (lane & 15);
      #pragma unroll
      for (int q=0; q<4; q++){
        int o = rt*16 + (lane >> 4)*4 + q;     // C/D layout (m89)
        buf[o*264 + xxo] = (_Float16)(acc[rt][cl][q] + cb[o]);
      }
    }
  __syncthreads();
  {
    int o = t >> 3, xb = (t & 7)*32;
    #pragma unroll
    for (int v4=0; v4<4; v4++){
      f16x8 vv = *(const f16x8*)(buf + o*264 + xb + v4*8);
      *(f16x8*)(tout + hbase + (size_t)o*CST + xb + v4*8) = vv;
    }
  }
  if (t < CH*2){
    int oo = t >> 1, st = t & 1;
    float s = red[oo][0][st] + red[oo][1][st] + red[oo][2][st] + red[oo][3][st];
    partials[((size_t)b*HH + y)*64 + t] = s;
  }
}

// ---------------- deterministic stats reduce -> scale/shift ----------------
__global__ void __launch_bounds__(512) k_stats(
    const float* __restrict__ partials,
    const float* __restrict__ g, const float* __restrict__ bb,
    float* __restrict__ bnp){
  __shared__ float acc[512];
  int o = blockIdx.x, t = threadIdx.x;
  int half = t >> 8, j = t & 255;
  float s = 0.f;
  for (int k=j; k<BATCH*HH; k+=256) s += partials[(size_t)k*64 + o*2 + half];
  acc[t] = s;
  __syncthreads();
  for (int w2=128; w2>0; w2>>=1){
    if (j < w2) acc[t] += acc[t+w2];
    __syncthreads();
  }
  if (t == 0){
    const float N = (float)BATCH * (float)(HH*HH);
    float mean = acc[0] / N;
    float var  = acc[256] / N - mean*mean;
    float iv = rsqrtf(var + 1e-5f);
    float scv = g[o]*iv;
    bnp[o]      = scv;
    bnp[CH + o] = bb[o] - mean*scv;
  }
}

// ------- final MFMA: BN(l3) + fc1 + relu + fc2, quadrant only --------------
__global__ void __launch_bounds__(256) k_final(
    const _Float16* __restrict__ tb, const float* __restrict__ bnp,
    const _Float16* __restrict__ W1h, const _Float16* __restrict__ W1l,
    const float* __restrict__ b1, const float* __restrict__ w2,
    const float* __restrict__ b2, float* __restrict__ out){
  __shared__ _Float16 Vf[128][40];      // pixel-major, 80B row stride
  int yq = blockIdx.x, b = blockIdx.y, t = threadIdx.x;
  int y = (SS-1) + yq;
  for (int i=t; i<CH*SS; i+=256){
    int c = i >> 7, xx = i & 127;
    float v = (float)tb[((size_t)(b*CH + c)*HH + y)*RST + (SS-1) + xx]
              * bnp[c] + bnp[CH+c];
    Vf[xx][c] = (_Float16)v;
  }
  __syncthreads();
  int w = t >> 6, lane = t & 63;
  int prow = lane & 15, koff = (lane >> 4)*8, col = lane & 15;
  f16x8 a0 = *(const f16x8*)&Vf[w*32 + prow][koff];
  f16x8 a1 = *(const f16x8*)&Vf[w*32 + 16 + prow][koff];
  float s0[4] = {0.f,0.f,0.f,0.f}, s1[4] = {0.f,0.f,0.f,0.f};
  #pragma unroll
  for (int nt=0; nt<8; nt++){
    f16x8 bh = *(const f16x8*)(W1h + ((size_t)nt*64 + lane)*8);
    f16x8 bl = *(const f16x8*)(W1l + ((size_t)nt*64 + lane)*8);
    f32x4 acc0 = {0.f,0.f,0.f,0.f}, acc1 = {0.f,0.f,0.f,0.f};
    acc0 = __builtin_amdgcn_mfma_f32_16x16x32_f16(a0, bh, acc0, 0,0,0);
    acc0 = __builtin_amdgcn_mfma_f32_16x16x32_f16(a0, bl, acc0, 0,0,0);
    acc1 = __builtin_amdgcn_mfma_f32_16x16x32_f16(a1, bh, acc1, 0,0,0);
    acc1 = __builtin_amdgcn_mfma_f32_16x16x32_f16(a1, bl, acc1, 0,0,0);
    float b1v = b1[nt*16 + col];
    float w2v = w2[nt*16 + col];
    #pragma unroll
    for (int q=0; q<4; q++){
      s0[q] += fmaxf(acc0[q] + b1v, 0.f)*w2v;
      s1[q] += fmaxf(acc1[q] + b1v, 0.f)*w2v;
    }
  }
  float o2b = b2[0];
  #pragma unroll
  for (int q=0; q<4; q++){
    float v0 = s0[q], v1 = s1[q];
    #pragma unroll
    for (int off=8; off>0; off>>=1){
      v0 += __shfl_xor(v0, off, 16);
      v1 += __shfl_xor(v1, off, 16);
    }
    if (col == (unsigned)q){           // one writer per pixel, deterministic
      int p0 = w*32 + (lane >> 4)*4 + q;
      int p1 = p0 + 16;
      float r0 = v0 + o2b, r1 = v1 + o2b;
      int ob = (b*DC)*SS*SS + yq*SS;
      #pragma unroll
      for (int cc=0; cc<DC; cc++){
        out[ob + cc*SS*SS + p0] = r0;
        out[ob + cc*SS*SS + p1] = r1;
      }
    }
  }
}

extern "C" void kernel_launch(void* const* d_in, const int* in_sizes, int n_in,
                              void* d_out, int out_size, void* d_ws, size_t ws_size,
                              hipStream_t stream) {
  (void)in_sizes; (void)n_in; (void)out_size; (void)ws_size;
  const float* x      = (const float*)d_in[0];
  const float* fc0_w  = (const float*)d_in[1];
  const float* fc0_b  = (const float*)d_in[2];
  const float* spec_w = (const float*)d_in[3];
  const float* conv_w = (const float*)d_in[4];
  const float* conv_b = (const float*)d_in[5];
  const float* bn_g   = (const float*)d_in[6];
  const float* bn_b   = (const float*)d_in[7];
  const float* fc1_w  = (const float*)d_in[8];
  const float* fc1_b  = (const float*)d_in[9];
  const float* fc2_w  = (const float*)d_in[10];
  const float* fc2_b  = (const float*)d_in[11];
  float* out = (float*)d_out;
  float* ws  = (float*)d_ws;

  // field: 16*32*255*256 f16 = 33,423,360 halves = 16,711,680 floats (~64 MiB)
  _Float16* field = (_Float16*)ws;
  float* Gbuf  = ws + 16711680;                        // NROWS*24 = 3,133,440
  float* Xf    = Gbuf + (size_t)NROWS*24;              // 294,912
  float* parts = Xf   + (size_t)BATCH*CH*KY24*M2*2;    // 261,120
  float* bnp   = parts + (size_t)64*BATCH*HH;          // 5 slots x 64
  _Float16* Whi = (_Float16*)(bnp + 5*64);             // 8192 halves each
  _Float16* Wlo = Whi + 2*8*64*8;
  _Float16* Th  = Wlo + 2*8*64*8;
  _Float16* Tl  = Th  + 16*64*8;
  _Float16* W1h = Tl  + 16*64*8;                       // 4096 halves each
  _Float16* W1l = W1h + 8*64*8;

  k_tabs<<<10, 256, 0, stream>>>(fc1_w, Whi, Wlo, Th, Tl, W1h, W1l);
  k_fc0<<<dim3(HH, BATCH), 256, 0, stream>>>(x, fc0_w, fc0_b, field, bnp);

  const size_t wstride = (size_t)2*CH*CH*M1*M2*2;      // per-layer spec_w elems
  for (int l=0; l<4; l++){
    const float* bnin = bnp + (size_t)l*64;            // BN of layer l-1 (or id)
    int relu = (l >= 1);                               // ReLU after layers 0..2
    k_fwd  <<<BATCH*CH, 256, 0, stream>>>(field, Xf, Whi, Wlo, bnin, relu);
    k_specmix<<<dim3(CH, BATCH), 256, 0, stream>>>(Xf, spec_w + (size_t)l*wstride, Gbuf);
    k_fuse <<<dim3(HH, BATCH), 256, 0, stream>>>(field, Gbuf, conv_w + l*CH*CH,
                                                 conv_b + l*CH, field, parts,
                                                 Th, Tl, bnin, relu);
    k_stats<<<CH, 512, 0, stream>>>(parts, bn_g + l*CH, bn_b + l*CH,
                                    bnp + (size_t)(l+1)*64);
  }
  k_final<<<dim3(SS, BATCH), 256, 0, stream>>>(field, bnp + 4*64, W1h, W1l,
                                               fc1_b, fc2_w, fc2_b, out);
}

// Round 16
// 528.188 us; speedup vs baseline: 1.1934x; 1.0119x over previous
//
#include <hip/hip_runtime.h>

#define BATCH 16
#define CH 32
#define DC 3
#define SS 128
#define HH 255
#define RST 256                 // padded row stride (f16, 512B-aligned rows)
#define CST (HH*RST)            // channel stride in field
#define M1 12
#define M2 12
#define KY24 (2*M1)
#define NROWS (BATCH*CH*HH)
#define TWOPI_N 0.02463994238463573f   // 2*pi/255

typedef __attribute__((ext_vector_type(8))) _Float16 f16x8;
typedef __attribute__((ext_vector_type(4))) float f32x4;

// ------- mirror + fc0 lift, vectorized f16x8 stores ------------------------
__global__ void __launch_bounds__(256) k_fc0(
    const float* __restrict__ x, const float* __restrict__ w,
    const float* __restrict__ bias, _Float16* __restrict__ h){
  int y = blockIdx.x, b = blockIdx.y, t = threadIdx.x;
  int d = t >> 3, g = t & 7;
  int iy = (y >= SS-1) ? y - (SS-1) : (SS-1) - y;
  float w0 = w[d], w1 = w[CH+d], w2 = w[2*CH+d], bs = bias[d];
  const float* xp = x + (size_t)(b*DC)*SS*SS + iy*SS;
  size_t obase = ((size_t)(b*CH + d)*HH + y)*RST;
  #pragma unroll
  for (int i=0; i<4; i++){
    int x0 = i*64 + g*8;
    f16x8 pk;
    #pragma unroll
    for (int u=0; u<8; u++){
      int xx = x0 + u;
      float v = 0.f;
      if (xx < HH){
        int ix = (xx >= SS-1) ? xx - (SS-1) : (SS-1) - xx;
        float sgn = ((y >= SS-1) == (xx >= SS-1)) ? 1.f : -1.f;
        v = bs + sgn*(xp[ix]*w0 + xp[SS*SS+ix]*w1 + xp[2*SS*SS+ix]*w2);
      }
      pk[u] = (_Float16)v;
    }
    *(f16x8*)(h + obase + x0) = pk;
  }
}

// ------- all weight/twiddle tables in one kernel ---------------------------
__global__ void __launch_bounds__(256) k_tabs(
    const float* __restrict__ w1,
    _Float16* __restrict__ Whi, _Float16* __restrict__ Wlo,
    _Float16* __restrict__ Th,  _Float16* __restrict__ Tl,
    _Float16* __restrict__ W1h, _Float16* __restrict__ W1l){
  int bi = blockIdx.x;
  if (bi < 4){
    int t = bi*256 + threadIdx.x;          // t < 1024 = 2*8*64
    int ct = t >> 9, ks = (t >> 6) & 7, lane = t & 63;
    int col = ct*16 + (lane & 15);
    int kb = ks*32 + (lane >> 4)*8;
    for (int j=0; j<8; j++){
      int k = kb + j;
      float w = 0.f;
      if (k < 255 && col < 24){
        int m = col >> 1;
        float ang = TWOPI_N * (float)((k*m) % 255);
        w = (col & 1) ? -sinf(ang) : cosf(ang);
      }
      _Float16 hi = (_Float16)w;
      Whi[t*8+j] = hi;
      Wlo[t*8+j] = (_Float16)(w - (float)hi);
    }
  } else if (bi < 8){
    int t = (bi-4)*256 + threadIdx.x;      // t < 1024 = 16*64
    int ct = t >> 6, lane = t & 63;
    int xx = ct*16 + (lane & 15);
    int jbase = (lane >> 4)*8;
    for (int j=0; j<8; j++){
      int jg = jbase + j;
      float v = 0.f;
      if (xx < HH && jg <= 22){
        if (jg == 0) v = 1.f;
        else if (jg & 1){ int kx=(jg+1)>>1; v =  cosf(TWOPI_N*(float)((kx*xx)%255)); }
        else            { int kx= jg>>1;    v = -sinf(TWOPI_N*(float)((kx*xx)%255)); }
      }
      _Float16 hi = (_Float16)v;
      Th[t*8+j] = hi;
      Tl[t*8+j] = (_Float16)(v - (float)hi);
    }
  } else {
    int t = (bi-8)*256 + threadIdx.x;      // t < 512 = 8*64
    int nt = t >> 6, lane = t & 63;
    int col = nt*16 + (lane & 15);
    int kb = (lane >> 4)*8;
    for (int j=0; j<8; j++){
      float v = w1[(kb+j)*128 + col];
      _Float16 hi = (_Float16)v;
      W1h[t*8+j] = hi;
      W1l[t*8+j] = (_Float16)(v - (float)hi);
    }
  }
}

// ----- fused per-channel BN-stats + forward DFT (W via MFMA, H via recur) --
// one block per (b,c). Computes this channel's BN scale/shift from parts
// (fixed-order -> bitwise identical across blocks); b==0 publishes to bnpo.
__global__ void __launch_bounds__(256) k_fwd(
    const _Float16* __restrict__ h, float* __restrict__ Xf,
    const _Float16* __restrict__ Whi, const _Float16* __restrict__ Wlo,
    const float* __restrict__ parts, const float* __restrict__ g,
    const float* __restrict__ bb, float* __restrict__ bnpo,
    int l0, int relu){
  __shared__ float lr[HH][26];           // [y][kx*2 + re/im], 26.5 KB
  __shared__ float rs[256][2];
  int t = threadIdx.x, bc = blockIdx.x;
  int wid = t >> 6, lane = t & 63;
  int c = bc & (CH-1), b = bc >> 5;
  float sc = 1.f, sh = 0.f;
  if (!l0){
    float s1 = 0.f, s2 = 0.f;
    for (int k=t; k<BATCH*HH; k+=256){
      float2 p2 = *(const float2*)(parts + (size_t)k*64 + c*2);
      s1 += p2.x; s2 += p2.y;
    }
    rs[t][0] = s1; rs[t][1] = s2;
    __syncthreads();
    for (int w2=128; w2>0; w2>>=1){
      if (t < w2){ rs[t][0] += rs[t+w2][0]; rs[t][1] += rs[t+w2][1]; }
      __syncthreads();
    }
    const float N = (float)BATCH * (float)(HH*HH);
    float mean = rs[0][0] / N;
    float var  = rs[0][1] / N - mean*mean;
    float iv = rsqrtf(var + 1e-5f);
    sc = g[c]*iv;
    sh = bb[c] - mean*sc;
    __syncthreads();                     // rs reuse safety (none, but cheap)
  }
  if (b == 0 && t == 0){ bnpo[c] = sc; bnpo[CH+c] = sh; }
  _Float16 sch = (_Float16)sc, shh = (_Float16)sh;
  f16x8 scv, shv;
  #pragma unroll
  for (int u=0; u<8; u++){ scv[u]=sch; shv[u]=shh; }
  const _Float16* base = h + (size_t)bc*CST;
  int koff = (lane >> 4)*8;
  #pragma unroll
  for (int it=0; it<4; it++){
    int y0 = it*64 + wid*16;
    int yr = y0 + (lane & 15);
    int ycl = (yr < HH) ? yr : HH-1;     // clamp pad row (output discarded)
    const _Float16* rp = base + (size_t)ycl*RST;
    f16x8 av[8];
    #pragma unroll
    for (int ks=0; ks<8; ks++)
      av[ks] = *(const f16x8*)(rp + ks*32 + koff);
    f32x4 acc0 = {0.f,0.f,0.f,0.f};
    f32x4 acc1 = {0.f,0.f,0.f,0.f};
    #pragma unroll
    for (int ks=0; ks<8; ks++){
      f16x8 a = av[ks]*scv + shv;
      if (relu){
        #pragma unroll
        for (int u=0; u<8; u++) a[u] = (a[u] > (_Float16)0.f) ? a[u] : (_Float16)0.f;
      }
      f16x8 b0h = *(const f16x8*)(Whi + ((size_t)(0*8+ks)*64 + lane)*8);
      f16x8 b0l = *(const f16x8*)(Wlo + ((size_t)(0*8+ks)*64 + lane)*8);
      f16x8 b1h = *(const f16x8*)(Whi + ((size_t)(1*8+ks)*64 + lane)*8);
      f16x8 b1l = *(const f16x8*)(Wlo + ((size_t)(1*8+ks)*64 + lane)*8);
      acc0 = __builtin_amdgcn_mfma_f32_16x16x32_f16(a, b0h, acc0, 0,0,0);
      acc0 = __builtin_amdgcn_mfma_f32_16x16x32_f16(a, b0l, acc0, 0,0,0);
      acc1 = __builtin_amdgcn_mfma_f32_16x16x32_f16(a, b1h, acc1, 0,0,0);
      acc1 = __builtin_amdgcn_mfma_f32_16x16x32_f16(a, b1l, acc1, 0,0,0);
    }
    int colq = lane & 15;
    int rq = y0 + (lane >> 4)*4;
    #pragma unroll
    for (int q=0; q<4; q++)
      if (rq+q < HH) lr[rq+q][colq] = acc0[q];
    if (colq < 8){
      #pragma unroll
      for (int q=0; q<4; q++)
        if (rq+q < HH) lr[rq+q][16+colq] = acc1[q];
    }
  }
  __syncthreads();
  // phase 2: column DFT, 288 items over 256 threads
  for (int p = t; p < KY24*M2; p += 256){
    int ky = p / M2, kx = p - (p/M2)*M2;
    int freq = (ky < M1) ? ky : (HH - KY24 + ky);  // 0..11 or 243..254
    float ang = TWOPI_N * (float)freq;
    float c1 = cosf(ang), s1 = sinf(ang);
    float cr=1.f, sr=0.f, ar=0.f, ai=0.f;
    for (int y=0; y<HH; y++){
      float rr = lr[y][kx*2], ri = lr[y][kx*2+1];
      ar += rr*cr + ri*sr;   // * e^{-i theta}
      ai += ri*cr - rr*sr;
      float cn = cr*c1 - sr*s1;
      sr = sr*c1 + cr*s1;
      cr = cn;
    }
    const float inv = 1.0f/255.0f;
    int o = (bc*KY24 + ky)*(M2*2) + kx*2;
    Xf[o]   = ar*inv;
    Xf[o+1] = ai*inv;
  }
}

// ------- fused channel-mix + inverse along H: Xf -> G[bo][y][kx] -----------
__global__ void __launch_bounds__(256) k_specmix(
    const float* __restrict__ Xf, const float* __restrict__ w,
    float* __restrict__ G){
  __shared__ float ly[KY24][M2][2];
  int o = blockIdx.x, b = blockIdx.y, t = threadIdx.x;
  for (int m = t; m < KY24*M2; m += 256){
    int ky = m / M2, kx = m - (m/M2)*M2;
    int blk = (ky < M1) ? 0 : 1;
    int m1 = ky - blk*M1;
    const float* wp = w + (size_t)blk*(CH*CH*M1*M2*2)
                        + (size_t)o*(M1*M2*2) + m1*(M2*2) + kx*2;
    const float* xp = Xf + ((size_t)(b*CH)*KY24 + ky)*(M2*2) + kx*2;
    float ar=0.f, ai=0.f;
    for (int i=0;i<CH;i++){
      float xr = xp[0], xi = xp[1];
      float wr = wp[0], wi = wp[1];
      ar += xr*wr - xi*wi;
      ai += xr*wi + xi*wr;
      xp += KY24*M2*2;
      wp += CH*M1*M2*2;
    }
    ly[ky][kx][0] = ar;
    ly[ky][kx][1] = ai;
  }
  __syncthreads();
  const float inv = 1.0f/255.0f;
  size_t bo = (size_t)b*CH + o;
  for (int p=t; p<HH*M2; p+=256){
    int y = p/M2, kx = p - (p/M2)*M2;
    float ang = TWOPI_N * (float)y;
    float c1 = cosf(ang), s1 = sinf(ang);
    float ar = ly[0][kx][0], ai = ly[0][kx][1];
    float c = c1, s = s1;
    #pragma unroll
    for (int k=1; k<=11; k++){
      float yr = ly[k][kx][0],     yi = ly[k][kx][1];
      ar += yr*c - yi*s;                 // * T_k
      ai += yr*s + yi*c;
      float zr = ly[24-k][kx][0],  zi = ly[24-k][kx][1];
      ar += zr*c + zi*s;                 // * conj(T_k)
      ai += zi*c - zr*s;
      float cn = c*c1 - s*s1;
      s = s*c1 + c*s1;
      c = cn;
    }
    {
      float zr = ly[12][kx][0], zi = ly[12][kx][1];   // freq -12: conj(T_12)
      ar += zr*c + zi*s;
      ai += zi*c - zr*s;
    }
    float f = (kx==0) ? inv : 2.0f*inv;
    size_t og = (bo*HH + y)*(M2*2) + kx*2;
    G[og]   = ar*f;
    G[og+1] = ai*f;
  }
}

// ------- fused MFMA (1 row/block): conv + inv-W + partials -----------------
__global__ void __launch_bounds__(256) k_fuse(
    const _Float16* __restrict__ h, const float* __restrict__ G,
    const float* __restrict__ cw, const float* __restrict__ cb,
    _Float16* __restrict__ tout, float* __restrict__ partials,
    const _Float16* __restrict__ Th, const _Float16* __restrict__ Tl,
    const float* __restrict__ bnp, int relu){
  __shared__ _Float16 buf[8448];   // Bf: (ct*65+lane)*8+j ; Of: o*264+xx
  __shared__ float red[CH][4][2];
  int t = threadIdx.x;
  int y = blockIdx.x, b = blockIdx.y;
  size_t hbase = (size_t)(b*CH*HH + y)*RST;
  int cS = t >> 5, xg = t & 31;
  f16x8 ld[4];
  #pragma unroll
  for (int it=0; it<4; it++)
    ld[it] = *(const f16x8*)(h + hbase + (size_t)(it*8 + cS)*CST + xg*8);
  int w = t >> 6, lane = t & 63;
  int arow = lane & 15, koff = (lane >> 4)*8;
  f16x8 a0h[2], a0l[2], a1[2];
  #pragma unroll
  for (int rt=0; rt<2; rt++){
    int o = rt*16 + arow;
    #pragma unroll
    for (int j=0; j<8; j++){
      float v = cw[o*CH + koff + j];
      _Float16 hi = (_Float16)v;
      a0h[rt][j] = hi;
      a0l[rt][j] = (_Float16)(v - (float)hi);
    }
    const float* gp = G + ((size_t)(b*CH+o)*HH + y)*24;
    #pragma unroll
    for (int j=0; j<8; j++){
      int jg = koff + j;                 // jg>=23: T rows are zero -> don't care
      float v = (jg==0) ? gp[0] : gp[jg+1];
      a1[rt][j] = (_Float16)v;
    }
  }
  #pragma unroll
  for (int it=0; it<4; it++){
    int c = it*8 + cS;
    _Float16 sc_ = (_Float16)bnp[c], sh_ = (_Float16)bnp[CH+c];
    f16x8 scv, shv;
    #pragma unroll
    for (int u=0; u<8; u++){ scv[u]=sc_; shv[u]=sh_; }
    f16x8 z = ld[it]*scv + shv;
    if (relu){
      #pragma unroll
      for (int u=0; u<8; u++) z[u] = (z[u] > (_Float16)0.f) ? z[u] : (_Float16)0.f;
    }
    int base = ((xg>>1)*65 + ((xg&1)*8) + ((c>>3)<<4))*8 + (c&7);
    #pragma unroll
    for (int u=0; u<8; u++) buf[base + u*8] = z[u];
  }
  __syncthreads();
  f32x4 acc[2][4];
  #pragma unroll
  for (int rt=0; rt<2; rt++)
    #pragma unroll
    for (int cl=0; cl<4; cl++) acc[rt][cl] = (f32x4){0.f,0.f,0.f,0.f};
  #pragma unroll
  for (int cl=0; cl<4; cl++){
    int ct = w*4 + cl;
    f16x8 bd = *(const f16x8*)(buf + ((size_t)ct*65 + lane)*8);
    f16x8 th = *(const f16x8*)(Th + ((size_t)ct*64 + lane)*8);
    f16x8 tl = *(const f16x8*)(Tl + ((size_t)ct*64 + lane)*8);
    #pragma unroll
    for (int rt=0; rt<2; rt++){
      acc[rt][cl] = __builtin_amdgcn_mfma_f32_16x16x32_f16(a0h[rt], bd, acc[rt][cl], 0,0,0);
      acc[rt][cl] = __builtin_amdgcn_mfma_f32_16x16x32_f16(a0l[rt], bd, acc[rt][cl], 0,0,0);
      acc[rt][cl] = __builtin_amdgcn_mfma_f32_16x16x32_f16(a1[rt], th, acc[rt][cl], 0,0,0);
      acc[rt][cl] = __builtin_amdgcn_mfma_f32_16x16x32_f16(a1[rt], tl, acc[rt][cl], 0,0,0);
    }
  }
  #pragma unroll
  for (int rt=0; rt<2; rt++)
    #pragma unroll
    for (int q=0; q<4; q++){
      float v1 = 0.f, v2 = 0.f;
      #pragma unroll
      for (int cl=0; cl<4; cl++){
        int xxo = (w*4 + cl)*16 + (lane & 15);
        int o = rt*16 + (lane >> 4)*4 + q;
        float v = acc[rt][cl][q] + cb[o];
        float vv = (xxo < HH) ? v : 0.f;
        v1 += vv; v2 += vv*vv;
      }
      #pragma unroll
      for (int off=8; off>0; off>>=1){
        v1 += __shfl_xor(v1, off, 16);
        v2 += __shfl_xor(v2, off, 16);
      }
      if ((lane & 15) == 0){
        int o = rt*16 + (lane >> 4)*4 + q;
        red[o][w][0] = v1;
        red[o][w][1] = v2;
      }
    }
  __syncthreads();      // all Bf reads done -> safe to overwrite buf as Of
  #pragma unroll
  for (int rt=0; rt<2; rt++)
    #pragma unroll
    for (int cl=0; cl<4; cl++){
      int xxo = (w*4 + cl)*16 + (lane & 15);
      #pragma unroll
      for (int q=0; q<4; q++){
        int o = rt*16 + (lane >> 4)*4 + q;     // C/D layout (m89)
        buf[o*264 + xxo] = (_Float16)(acc[rt][cl][q] + cb[o]);
      }
    }
  __syncthreads();
  {
    int o = t >> 3, xb = (t & 7)*32;
    #pragma unroll
    for (int v4=0; v4<4; v4++){
      f16x8 vv = *(const f16x8*)(buf + o*264 + xb + v4*8);
      *(f16x8*)(tout + hbase + (size_t)o*CST + xb + v4*8) = vv;
    }
  }
  if (t < CH*2){
    int oo = t >> 1, st = t & 1;
    float s = red[oo][0][st] + red[oo][1][st] + red[oo][2][st] + red[oo][3][st];
    partials[((size_t)b*HH + y)*64 + t] = s;
  }
}

// ------ deterministic stats reduce -> scale/shift (final layer only) -------
__global__ void __launch_bounds__(512) k_stats(
    const float* __restrict__ partials,
    const float* __restrict__ g, const float* __restrict__ bb,
    float* __restrict__ bnp){
  __shared__ float acc[512];
  int o = blockIdx.x, t = threadIdx.x;
  int half = t >> 8, j = t & 255;
  float s = 0.f;
  for (int k=j; k<BATCH*HH; k+=256) s += partials[(size_t)k*64 + o*2 + half];
  acc[t] = s;
  __syncthreads();
  for (int w2=128; w2>0; w2>>=1){
    if (j < w2) acc[t] += acc[t+w2];
    __syncthreads();
  }
  if (t == 0){
    const float N = (float)BATCH * (float)(HH*HH);
    float mean = acc[0] / N;
    float var  = acc[256] / N - mean*mean;
    float iv = rsqrtf(var + 1e-5f);
    float scv = g[o]*iv;
    bnp[o]      = scv;
    bnp[CH + o] = bb[o] - mean*scv;
  }
}

// ------- final MFMA: BN(l3) + fc1 + relu + fc2, quadrant only --------------
__global__ void __launch_bounds__(256) k_final(
    const _Float16* __restrict__ tb, const float* __restrict__ bnp,
    const _Float16* __restrict__ W1h, const _Float16* __restrict__ W1l,
    const float* __restrict__ b1, const float* __restrict__ w2,
    const float* __restrict__ b2, float* __restrict__ out){
  __shared__ _Float16 Vf[128][40];      // pixel-major, 80B row stride
  int yq = blockIdx.x, b = blockIdx.y, t = threadIdx.x;
  int y = (SS-1) + yq;
  for (int i=t; i<CH*SS; i+=256){
    int c = i >> 7, xx = i & 127;
    float v = (float)tb[((size_t)(b*CH + c)*HH + y)*RST + (SS-1) + xx]
              * bnp[c] + bnp[CH+c];
    Vf[xx][c] = (_Float16)v;
  }
  __syncthreads();
  int w = t >> 6, lane = t & 63;
  int prow = lane & 15, koff = (lane >> 4)*8, col = lane & 15;
  f16x8 a0 = *(const f16x8*)&Vf[w*32 + prow][koff];
  f16x8 a1 = *(const f16x8*)&Vf[w*32 + 16 + prow][koff];
  float s0[4] = {0.f,0.f,0.f,0.f}, s1[4] = {0.f,0.f,0.f,0.f};
  #pragma unroll
  for (int nt=0; nt<8; nt++){
    f16x8 bh = *(const f16x8*)(W1h + ((size_t)nt*64 + lane)*8);
    f16x8 bl = *(const f16x8*)(W1l + ((size_t)nt*64 + lane)*8);
    f32x4 acc0 = {0.f,0.f,0.f,0.f}, acc1 = {0.f,0.f,0.f,0.f};
    acc0 = __builtin_amdgcn_mfma_f32_16x16x32_f16(a0, bh, acc0, 0,0,0);
    acc0 = __builtin_amdgcn_mfma_f32_16x16x32_f16(a0, bl, acc0, 0,0,0);
    acc1 = __builtin_amdgcn_mfma_f32_16x16x32_f16(a1, bh, acc1, 0,0,0);
    acc1 = __builtin_amdgcn_mfma_f32_16x16x32_f16(a1, bl, acc1, 0,0,0);
    float b1v = b1[nt*16 + col];
    float w2v = w2[nt*16 + col];
    #pragma unroll
    for (int q=0; q<4; q++){
      s0[q] += fmaxf(acc0[q] + b1v, 0.f)*w2v;
      s1[q] += fmaxf(acc1[q] + b1v, 0.f)*w2v;
    }
  }
  float o2b = b2[0];
  #pragma unroll
  for (int q=0; q<4; q++){
    float v0 = s0[q], v1 = s1[q];
    #pragma unroll
    for (int off=8; off>0; off>>=1){
      v0 += __shfl_xor(v0, off, 16);
      v1 += __shfl_xor(v1, off, 16);
    }
    if (col == (unsigned)q){           // one writer per pixel, deterministic
      int p0 = w*32 + (lane >> 4)*4 + q;
      int p1 = p0 + 16;
      float r0 = v0 + o2b, r1 = v1 + o2b;
      int ob = (b*DC)*SS*SS + yq*SS;
      #pragma unroll
      for (int cc=0; cc<DC; cc++){
        out[ob + cc*SS*SS + p0] = r0;
        out[ob + cc*SS*SS + p1] = r1;
      }
    }
  }
}

extern "C" void kernel_launch(void* const* d_in, const int* in_sizes, int n_in,
                              void* d_out, int out_size, void* d_ws, size_t ws_size,
                              hipStream_t stream) {
  (void)in_sizes; (void)n_in; (void)out_size; (void)ws_size;
  const float* x      = (const float*)d_in[0];
  const float* fc0_w  = (const float*)d_in[1];
  const float* fc0_b  = (const float*)d_in[2];
  const float* spec_w = (const float*)d_in[3];
  const float* conv_w = (const float*)d_in[4];
  const float* conv_b = (const float*)d_in[5];
  const float* bn_g   = (const float*)d_in[6];
  const float* bn_b   = (const float*)d_in[7];
  const float* fc1_w  = (const float*)d_in[8];
  const float* fc1_b  = (const float*)d_in[9];
  const float* fc2_w  = (const float*)d_in[10];
  const float* fc2_b  = (const float*)d_in[11];
  float* out = (float*)d_out;
  float* ws  = (float*)d_ws;

  // field: 16*32*255*256 f16 = 33,423,360 halves = 16,711,680 floats (~64 MiB)
  _Float16* field = (_Float16*)ws;
  float* Gbuf  = ws + 16711680;                        // NROWS*24 = 3,133,440
  float* Xf    = Gbuf + (size_t)NROWS*24;              // 294,912
  float* parts = Xf   + (size_t)BATCH*CH*KY24*M2*2;    // 261,120
  float* bnpF  = parts + (size_t)64*BATCH*HH;          // 64 (per-layer fuse BN)
  float* bnpL  = bnpF + 64;                            // 64 (final BN)
  _Float16* Whi = (_Float16*)(bnpL + 64);              // 8192 halves each
  _Float16* Wlo = Whi + 2*8*64*8;
  _Float16* Th  = Wlo + 2*8*64*8;
  _Float16* Tl  = Th  + 16*64*8;
  _Float16* W1h = Tl  + 16*64*8;                       // 4096 halves each
  _Float16* W1l = W1h + 8*64*8;

  k_tabs<<<10, 256, 0, stream>>>(fc1_w, Whi, Wlo, Th, Tl, W1h, W1l);
  k_fc0<<<dim3(HH, BATCH), 256, 0, stream>>>(x, fc0_w, fc0_b, field);

  const size_t wstride = (size_t)2*CH*CH*M1*M2*2;      // per-layer spec_w elems
  for (int l=0; l<4; l++){
    int l0 = (l == 0);
    int relu = (l >= 1);                               // ReLU after layers 0..2
    const float* gg = l0 ? bn_g : bn_g + (size_t)(l-1)*CH;
    const float* gb = l0 ? bn_b : bn_b + (size_t)(l-1)*CH;
    k_fwd  <<<BATCH*CH, 256, 0, stream>>>(field, Xf, Whi, Wlo,
                                          parts, gg, gb, bnpF, l0, relu);
    k_specmix<<<dim3(CH, BATCH), 256, 0, stream>>>(Xf, spec_w + (size_t)l*wstride, Gbuf);
    k_fuse <<<dim3(HH, BATCH), 256, 0, stream>>>(field, Gbuf, conv_w + l*CH*CH,
                                                 conv_b + l*CH, field, parts,
                                                 Th, Tl, bnpF, relu);
  }
  k_stats<<<CH, 512, 0, stream>>>(parts, bn_g + 3*CH, bn_b + 3*CH, bnpL);
  k_final<<<dim3(SS, BATCH), 256, 0, stream>>>(field, bnpL, W1h, W1l,
                                               fc1_b, fc2_w, fc2_b, out);
}

// Round 17
// 523.505 us; speedup vs baseline: 1.2040x; 1.0089x over previous
//
#include <hip/hip_runtime.h>

#define BATCH 16
#define CH 32
#define DC 3
#define SS 128
#define HH 255
#define RST 256                 // padded x stride per channel (f16)
#define FST ((size_t)CH*RST)    // stride per (b,y) row-group: 8192 halves
#define M1 12
#define M2 12
#define KY24 (2*M1)
#define NROWS (BATCH*CH*HH)
#define TWOPI_N 0.02463994238463573f   // 2*pi/255

typedef __attribute__((ext_vector_type(8))) _Float16 f16x8;
typedef __attribute__((ext_vector_type(4))) float f32x4;

// field layout: [b][y][c][x]  (c-inner: k_fuse/k_final blocks contiguous)

// ------- mirror + fc0 lift, vectorized f16x8 stores ------------------------
__global__ void __launch_bounds__(256) k_fc0(
    const float* __restrict__ x, const float* __restrict__ w,
    const float* __restrict__ bias, _Float16* __restrict__ h){
  int y = blockIdx.x, b = blockIdx.y, t = threadIdx.x;
  int d = t >> 3, g = t & 7;
  int iy = (y >= SS-1) ? y - (SS-1) : (SS-1) - y;
  float w0 = w[d], w1 = w[CH+d], w2 = w[2*CH+d], bs = bias[d];
  const float* xp = x + (size_t)(b*DC)*SS*SS + iy*SS;
  size_t obase = (size_t)(b*HH + y)*FST + (size_t)d*RST;
  #pragma unroll
  for (int i=0; i<4; i++){
    int x0 = i*64 + g*8;
    f16x8 pk;
    #pragma unroll
    for (int u=0; u<8; u++){
      int xx = x0 + u;
      float v = 0.f;
      if (xx < HH){
        int ix = (xx >= SS-1) ? xx - (SS-1) : (SS-1) - xx;
        float sgn = ((y >= SS-1) == (xx >= SS-1)) ? 1.f : -1.f;
        v = bs + sgn*(xp[ix]*w0 + xp[SS*SS+ix]*w1 + xp[2*SS*SS+ix]*w2);
      }
      pk[u] = (_Float16)v;
    }
    *(f16x8*)(h + obase + x0) = pk;
  }
}

// ------- all weight/twiddle tables in one kernel ---------------------------
__global__ void __launch_bounds__(256) k_tabs(
    const float* __restrict__ w1,
    _Float16* __restrict__ Whi, _Float16* __restrict__ Wlo,
    _Float16* __restrict__ Th,  _Float16* __restrict__ Tl,
    _Float16* __restrict__ W1h, _Float16* __restrict__ W1l){
  int bi = blockIdx.x;
  if (bi < 4){
    int t = bi*256 + threadIdx.x;          // t < 1024 = 2*8*64
    int ct = t >> 9, ks = (t >> 6) & 7, lane = t & 63;
    int col = ct*16 + (lane & 15);
    int kb = ks*32 + (lane >> 4)*8;
    for (int j=0; j<8; j++){
      int k = kb + j;
      float w = 0.f;
      if (k < 255 && col < 24){
        int m = col >> 1;
        float ang = TWOPI_N * (float)((k*m) % 255);
        w = (col & 1) ? -sinf(ang) : cosf(ang);
      }
      _Float16 hi = (_Float16)w;
      Whi[t*8+j] = hi;
      Wlo[t*8+j] = (_Float16)(w - (float)hi);
    }
  } else if (bi < 8){
    int t = (bi-4)*256 + threadIdx.x;      // t < 1024 = 16*64
    int ct = t >> 6, lane = t & 63;
    int xx = ct*16 + (lane & 15);
    int jbase = (lane >> 4)*8;
    for (int j=0; j<8; j++){
      int jg = jbase + j;
      float v = 0.f;
      if (xx < HH && jg <= 22){
        if (jg == 0) v = 1.f;
        else if (jg & 1){ int kx=(jg+1)>>1; v =  cosf(TWOPI_N*(float)((kx*xx)%255)); }
        else            { int kx= jg>>1;    v = -sinf(TWOPI_N*(float)((kx*xx)%255)); }
      }
      _Float16 hi = (_Float16)v;
      Th[t*8+j] = hi;
      Tl[t*8+j] = (_Float16)(v - (float)hi);
    }
  } else {
    int t = (bi-8)*256 + threadIdx.x;      // t < 512 = 8*64
    int nt = t >> 6, lane = t & 63;
    int col = nt*16 + (lane & 15);
    int kb = (lane >> 4)*8;
    for (int j=0; j<8; j++){
      float v = w1[(kb+j)*128 + col];
      _Float16 hi = (_Float16)v;
      W1h[t*8+j] = hi;
      W1l[t*8+j] = (_Float16)(v - (float)hi);
    }
  }
}

// ----- fused per-channel BN-stats + forward DFT (W via MFMA, H via recur) --
// one block per (b,c). Computes this channel's BN scale/shift from parts
// (fixed-order -> bitwise identical across blocks); b==0 publishes to bnpo.
__global__ void __launch_bounds__(256) k_fwd(
    const _Float16* __restrict__ h, float* __restrict__ Xf,
    const _Float16* __restrict__ Whi, const _Float16* __restrict__ Wlo,
    const float* __restrict__ parts, const float* __restrict__ g,
    const float* __restrict__ bb, float* __restrict__ bnpo,
    int l0, int relu){
  __shared__ float lr[HH][26];           // [y][kx*2 + re/im], 26.5 KB
  __shared__ float rs[256][2];
  int t = threadIdx.x, bc = blockIdx.x;
  int wid = t >> 6, lane = t & 63;
  int c = bc & (CH-1), b = bc >> 5;
  float sc = 1.f, sh = 0.f;
  if (!l0){
    float s1 = 0.f, s2 = 0.f;
    for (int k=t; k<BATCH*HH; k+=256){
      float2 p2 = *(const float2*)(parts + (size_t)k*64 + c*2);
      s1 += p2.x; s2 += p2.y;
    }
    rs[t][0] = s1; rs[t][1] = s2;
    __syncthreads();
    for (int w2=128; w2>0; w2>>=1){
      if (t < w2){ rs[t][0] += rs[t+w2][0]; rs[t][1] += rs[t+w2][1]; }
      __syncthreads();
    }
    const float N = (float)BATCH * (float)(HH*HH);
    float mean = rs[0][0] / N;
    float var  = rs[0][1] / N - mean*mean;
    float iv = rsqrtf(var + 1e-5f);
    sc = g[c]*iv;
    sh = bb[c] - mean*sc;
    __syncthreads();
  }
  if (b == 0 && t == 0){ bnpo[c] = sc; bnpo[CH+c] = sh; }
  _Float16 sch = (_Float16)sc, shh = (_Float16)sh;
  f16x8 scv, shv;
  #pragma unroll
  for (int u=0; u<8; u++){ scv[u]=sch; shv[u]=shh; }
  const _Float16* base = h + (size_t)b*HH*FST + (size_t)c*RST;
  int koff = (lane >> 4)*8;
  #pragma unroll
  for (int it=0; it<4; it++){
    int y0 = it*64 + wid*16;
    int yr = y0 + (lane & 15);
    int ycl = (yr < HH) ? yr : HH-1;     // clamp pad row (output discarded)
    const _Float16* rp = base + (size_t)ycl*FST;
    f16x8 av[8];
    #pragma unroll
    for (int ks=0; ks<8; ks++)
      av[ks] = *(const f16x8*)(rp + ks*32 + koff);
    f32x4 acc0 = {0.f,0.f,0.f,0.f};
    f32x4 acc1 = {0.f,0.f,0.f,0.f};
    #pragma unroll
    for (int ks=0; ks<8; ks++){
      f16x8 a = av[ks]*scv + shv;
      if (relu){
        #pragma unroll
        for (int u=0; u<8; u++) a[u] = (a[u] > (_Float16)0.f) ? a[u] : (_Float16)0.f;
      }
      f16x8 b0h = *(const f16x8*)(Whi + ((size_t)(0*8+ks)*64 + lane)*8);
      f16x8 b0l = *(const f16x8*)(Wlo + ((size_t)(0*8+ks)*64 + lane)*8);
      f16x8 b1h = *(const f16x8*)(Whi + ((size_t)(1*8+ks)*64 + lane)*8);
      f16x8 b1l = *(const f16x8*)(Wlo + ((size_t)(1*8+ks)*64 + lane)*8);
      acc0 = __builtin_amdgcn_mfma_f32_16x16x32_f16(a, b0h, acc0, 0,0,0);
      acc0 = __builtin_amdgcn_mfma_f32_16x16x32_f16(a, b0l, acc0, 0,0,0);
      acc1 = __builtin_amdgcn_mfma_f32_16x16x32_f16(a, b1h, acc1, 0,0,0);
      acc1 = __builtin_amdgcn_mfma_f32_16x16x32_f16(a, b1l, acc1, 0,0,0);
    }
    int colq = lane & 15;
    int rq = y0 + (lane >> 4)*4;
    #pragma unroll
    for (int q=0; q<4; q++)
      if (rq+q < HH) lr[rq+q][colq] = acc0[q];
    if (colq < 8){
      #pragma unroll
      for (int q=0; q<4; q++)
        if (rq+q < HH) lr[rq+q][16+colq] = acc1[q];
    }
  }
  __syncthreads();
  // phase 2: column DFT, 288 items over 256 threads
  for (int p = t; p < KY24*M2; p += 256){
    int ky = p / M2, kx = p - (p/M2)*M2;
    int freq = (ky < M1) ? ky : (HH - KY24 + ky);  // 0..11 or 243..254
    float ang = TWOPI_N * (float)freq;
    float c1 = cosf(ang), s1 = sinf(ang);
    float cr=1.f, sr=0.f, ar=0.f, ai=0.f;
    for (int y=0; y<HH; y++){
      float rr = lr[y][kx*2], ri = lr[y][kx*2+1];
      ar += rr*cr + ri*sr;   // * e^{-i theta}
      ai += ri*cr - rr*sr;
      float cn = cr*c1 - sr*s1;
      sr = sr*c1 + cr*s1;
      cr = cn;
    }
    const float inv = 1.0f/255.0f;
    int o = (bc*KY24 + ky)*(M2*2) + kx*2;
    Xf[o]   = ar*inv;
    Xf[o+1] = ai*inv;
  }
}

// ------- fused channel-mix + inverse along H: Xf -> G[bo][y][kx] -----------
__global__ void __launch_bounds__(256) k_specmix(
    const float* __restrict__ Xf, const float* __restrict__ w,
    float* __restrict__ G){
  __shared__ float ly[KY24][M2][2];
  int o = blockIdx.x, b = blockIdx.y, t = threadIdx.x;
  for (int m = t; m < KY24*M2; m += 256){
    int ky = m / M2, kx = m - (m/M2)*M2;
    int blk = (ky < M1) ? 0 : 1;
    int m1 = ky - blk*M1;
    const float* wp = w + (size_t)blk*(CH*CH*M1*M2*2)
                        + (size_t)o*(M1*M2*2) + m1*(M2*2) + kx*2;
    const float* xp = Xf + ((size_t)(b*CH)*KY24 + ky)*(M2*2) + kx*2;
    float ar=0.f, ai=0.f;
    for (int i=0;i<CH;i++){
      float xr = xp[0], xi = xp[1];
      float wr = wp[0], wi = wp[1];
      ar += xr*wr - xi*wi;
      ai += xr*wi + xi*wr;
      xp += KY24*M2*2;
      wp += CH*M1*M2*2;
    }
    ly[ky][kx][0] = ar;
    ly[ky][kx][1] = ai;
  }
  __syncthreads();
  const float inv = 1.0f/255.0f;
  size_t bo = (size_t)b*CH + o;
  for (int p=t; p<HH*M2; p+=256){
    int y = p/M2, kx = p - (p/M2)*M2;
    float ang = TWOPI_N * (float)y;
    float c1 = cosf(ang), s1 = sinf(ang);
    float ar = ly[0][kx][0], ai = ly[0][kx][1];
    float c = c1, s = s1;
    #pragma unroll
    for (int k=1; k<=11; k++){
      float yr = ly[k][kx][0],     yi = ly[k][kx][1];
      ar += yr*c - yi*s;                 // * T_k
      ai += yr*s + yi*c;
      float zr = ly[24-k][kx][0],  zi = ly[24-k][kx][1];
      ar += zr*c + zi*s;                 // * conj(T_k)
      ai += zi*c - zr*s;
      float cn = c*c1 - s*s1;
      s = s*c1 + c*s1;
      c = cn;
    }
    {
      float zr = ly[12][kx][0], zi = ly[12][kx][1];   // freq -12: conj(T_12)
      ar += zr*c + zi*s;
      ai += zi*c - zr*s;
    }
    float f = (kx==0) ? inv : 2.0f*inv;
    size_t og = (bo*HH + y)*(M2*2) + kx*2;
    G[og]   = ar*f;
    G[og+1] = ai*f;
  }
}

// ------- fused MFMA (1 row/block): conv + inv-W + partials -----------------
// field block-read and block-write are now fully contiguous (16 KB each)
__global__ void __launch_bounds__(256) k_fuse(
    const _Float16* __restrict__ h, const float* __restrict__ G,
    const float* __restrict__ cw, const float* __restrict__ cb,
    _Float16* __restrict__ tout, float* __restrict__ partials,
    const _Float16* __restrict__ Th, const _Float16* __restrict__ Tl,
    const float* __restrict__ bnp, int relu){
  __shared__ _Float16 buf[8448];   // Bf: (ct*65+lane)*8+j ; Of: o*264+xx
  __shared__ float red[CH][4][2];
  int t = threadIdx.x;
  int y = blockIdx.x, b = blockIdx.y;
  size_t hbase = (size_t)(b*HH + y)*FST;
  int cS = t >> 5, xg = t & 31;
  f16x8 ld[4];
  #pragma unroll
  for (int it=0; it<4; it++)
    ld[it] = *(const f16x8*)(h + hbase + (size_t)(it*8 + cS)*RST + xg*8);
  int w = t >> 6, lane = t & 63;
  int arow = lane & 15, koff = (lane >> 4)*8;
  f16x8 a0h[2], a0l[2], a1[2];
  #pragma unroll
  for (int rt=0; rt<2; rt++){
    int o = rt*16 + arow;
    #pragma unroll
    for (int j=0; j<8; j++){
      float v = cw[o*CH + koff + j];
      _Float16 hi = (_Float16)v;
      a0h[rt][j] = hi;
      a0l[rt][j] = (_Float16)(v - (float)hi);
    }
    const float* gp = G + ((size_t)(b*CH+o)*HH + y)*24;
    #pragma unroll
    for (int j=0; j<8; j++){
      int jg = koff + j;                 // jg>=23: T rows are zero -> don't care
      float v = (jg==0) ? gp[0] : gp[jg+1];
      a1[rt][j] = (_Float16)v;
    }
  }
  #pragma unroll
  for (int it=0; it<4; it++){
    int c = it*8 + cS;
    _Float16 sc_ = (_Float16)bnp[c], sh_ = (_Float16)bnp[CH+c];
    f16x8 scv, shv;
    #pragma unroll
    for (int u=0; u<8; u++){ scv[u]=sc_; shv[u]=sh_; }
    f16x8 z = ld[it]*scv + shv;
    if (relu){
      #pragma unroll
      for (int u=0; u<8; u++) z[u] = (z[u] > (_Float16)0.f) ? z[u] : (_Float16)0.f;
    }
    int base = ((xg>>1)*65 + ((xg&1)*8) + ((c>>3)<<4))*8 + (c&7);
    #pragma unroll
    for (int u=0; u<8; u++) buf[base + u*8] = z[u];
  }
  __syncthreads();
  f32x4 acc[2][4];
  #pragma unroll
  for (int rt=0; rt<2; rt++)
    #pragma unroll
    for (int cl=0; cl<4; cl++) acc[rt][cl] = (f32x4){0.f,0.f,0.f,0.f};
  #pragma unroll
  for (int cl=0; cl<4; cl++){
    int ct = w*4 + cl;
    f16x8 bd = *(const f16x8*)(buf + ((size_t)ct*65 + lane)*8);
    f16x8 th = *(const f16x8*)(Th + ((size_t)ct*64 + lane)*8);
    f16x8 tl = *(const f16x8*)(Tl + ((size_t)ct*64 + lane)*8);
    #pragma unroll
    for (int rt=0; rt<2; rt++){
      acc[rt][cl] = __builtin_amdgcn_mfma_f32_16x16x32_f16(a0h[rt], bd, acc[rt][cl], 0,0,0);
      acc[rt][cl] = __builtin_amdgcn_mfma_f32_16x16x32_f16(a0l[rt], bd, acc[rt][cl], 0,0,0);
      acc[rt][cl] = __builtin_amdgcn_mfma_f32_16x16x32_f16(a1[rt], th, acc[rt][cl], 0,0,0);
      acc[rt][cl] = __builtin_amdgcn_mfma_f32_16x16x32_f16(a1[rt], tl, acc[rt][cl], 0,0,0);
    }
  }
  #pragma unroll
  for (int rt=0; rt<2; rt++)
    #pragma unroll
    for (int q=0; q<4; q++){
      float v1 = 0.f, v2 = 0.f;
      #pragma unroll
      for (int cl=0; cl<4; cl++){
        int xxo = (w*4 + cl)*16 + (lane & 15);
        int o = rt*16 + (lane >> 4)*4 + q;
        float v = acc[rt][cl][q] + cb[o];
        float vv = (xxo < HH) ? v : 0.f;
        v1 += vv; v2 += vv*vv;
      }
      #pragma unroll
      for (int off=8; off>0; off>>=1){
        v1 += __shfl_xor(v1, off, 16);
        v2 += __shfl_xor(v2, off, 16);
      }
      if ((lane & 15) == 0){
        int o = rt*16 + (lane >> 4)*4 + q;
        red[o][w][0] = v1;
        red[o][w][1] = v2;
      }
    }
  __syncthreads();      // all Bf reads done -> safe to overwrite buf as Of
  #pragma unroll
  for (int rt=0; rt<2; rt++)
    #pragma unroll
    for (int cl=0; cl<4; cl++){
      int xxo = (w*4 + cl)*16 + (lane & 15);
      #pragma unroll
      for (int q=0; q<4; q++){
        int o = rt*16 + (lane >> 4)*4 + q;     // C/D layout (m89)
        buf[o*264 + xxo] = (_Float16)(acc[rt][cl][q] + cb[o]);
      }
    }
  __syncthreads();
  {
    int o = t >> 3, xb = (t & 7)*32;
    #pragma unroll
    for (int v4=0; v4<4; v4++){
      f16x8 vv = *(const f16x8*)(buf + o*264 + xb + v4*8);
      *(f16x8*)(tout + hbase + (size_t)o*RST + xb + v4*8) = vv;
    }
  }
  if (t < CH*2){
    int oo = t >> 1, st = t & 1;
    float s = red[oo][0][st] + red[oo][1][st] + red[oo][2][st] + red[oo][3][st];
    partials[((size_t)b*HH + y)*64 + t] = s;
  }
}

// ------ deterministic stats reduce -> scale/shift (final layer only) -------
__global__ void __launch_bounds__(512) k_stats(
    const float* __restrict__ partials,
    const float* __restrict__ g, const float* __restrict__ bb,
    float* __restrict__ bnp){
  __shared__ float acc[512];
  int o = blockIdx.x, t = threadIdx.x;
  int half = t >> 8, j = t & 255;
  float s = 0.f;
  for (int k=j; k<BATCH*HH; k+=256) s += partials[(size_t)k*64 + o*2 + half];
  acc[t] = s;
  __syncthreads();
  for (int w2=128; w2>0; w2>>=1){
    if (j < w2) acc[t] += acc[t+w2];
    __syncthreads();
  }
  if (t == 0){
    const float N = (float)BATCH * (float)(HH*HH);
    float mean = acc[0] / N;
    float var  = acc[256] / N - mean*mean;
    float iv = rsqrtf(var + 1e-5f);
    float scv = g[o]*iv;
    bnp[o]      = scv;
    bnp[CH + o] = bb[o] - mean*scv;
  }
}

// ------- final MFMA: BN(l3) + fc1 + relu + fc2, quadrant only --------------
__global__ void __launch_bounds__(256) k_final(
    const _Float16* __restrict__ tb, const float* __restrict__ bnp,
    const _Float16* __restrict__ W1h, const _Float16* __restrict__ W1l,
    const float* __restrict__ b1, const float* __restrict__ w2,
    const float* __restrict__ b2, float* __restrict__ out){
  __shared__ _Float16 Vf[128][40];      // pixel-major, 80B row stride
  int yq = blockIdx.x, b = blockIdx.y, t = threadIdx.x;
  int y = (SS-1) + yq;
  size_t rbase = (size_t)(b*HH + y)*FST;
  for (int i=t; i<CH*SS; i+=256){
    int c = i >> 7, xx = i & 127;
    float v = (float)tb[rbase + (size_t)c*RST + (SS-1) + xx]
              * bnp[c] + bnp[CH+c];
    Vf[xx][c] = (_Float16)v;
  }
  __syncthreads();
  int w = t >> 6, lane = t & 63;
  int prow = lane & 15, koff = (lane >> 4)*8, col = lane & 15;
  f16x8 a0 = *(const f16x8*)&Vf[w*32 + prow][koff];
  f16x8 a1 = *(const f16x8*)&Vf[w*32 + 16 + prow][koff];
  float s0[4] = {0.f,0.f,0.f,0.f}, s1[4] = {0.f,0.f,0.f,0.f};
  #pragma unroll
  for (int nt=0; nt<8; nt++){
    f16x8 bh = *(const f16x8*)(W1h + ((size_t)nt*64 + lane)*8);
    f16x8 bl = *(const f16x8*)(W1l + ((size_t)nt*64 + lane)*8);
    f32x4 acc0 = {0.f,0.f,0.f,0.f}, acc1 = {0.f,0.f,0.f,0.f};
    acc0 = __builtin_amdgcn_mfma_f32_16x16x32_f16(a0, bh, acc0, 0,0,0);
    acc0 = __builtin_amdgcn_mfma_f32_16x16x32_f16(a0, bl, acc0, 0,0,0);
    acc1 = __builtin_amdgcn_mfma_f32_16x16x32_f16(a1, bh, acc1, 0,0,0);
    acc1 = __builtin_amdgcn_mfma_f32_16x16x32_f16(a1, bl, acc1, 0,0,0);
    float b1v = b1[nt*16 + col];
    float w2v = w2[nt*16 + col];
    #pragma unroll
    for (int q=0; q<4; q++){
      s0[q] += fmaxf(acc0[q] + b1v, 0.f)*w2v;
      s1[q] += fmaxf(acc1[q] + b1v, 0.f)*w2v;
    }
  }
  float o2b = b2[0];
  #pragma unroll
  for (int q=0; q<4; q++){
    float v0 = s0[q], v1 = s1[q];
    #pragma unroll
    for (int off=8; off>0; off>>=1){
      v0 += __shfl_xor(v0, off, 16);
      v1 += __shfl_xor(v1, off, 16);
    }
    if (col == (unsigned)q){           // one writer per pixel, deterministic
      int p0 = w*32 + (lane >> 4)*4 + q;
      int p1 = p0 + 16;
      float r0 = v0 + o2b, r1 = v1 + o2b;
      int ob = (b*DC)*SS*SS + yq*SS;
      #pragma unroll
      for (int cc=0; cc<DC; cc++){
        out[ob + cc*SS*SS + p0] = r0;
        out[ob + cc*SS*SS + p1] = r1;
      }
    }
  }
}

extern "C" void kernel_launch(void* const* d_in, const int* in_sizes, int n_in,
                              void* d_out, int out_size, void* d_ws, size_t ws_size,
                              hipStream_t stream) {
  (void)in_sizes; (void)n_in; (void)out_size; (void)ws_size;
  const float* x      = (const float*)d_in[0];
  const float* fc0_w  = (const float*)d_in[1];
  const float* fc0_b  = (const float*)d_in[2];
  const float* spec_w = (const float*)d_in[3];
  const float* conv_w = (const float*)d_in[4];
  const float* conv_b = (const float*)d_in[5];
  const float* bn_g   = (const float*)d_in[6];
  const float* bn_b   = (const float*)d_in[7];
  const float* fc1_w  = (const float*)d_in[8];
  const float* fc1_b  = (const float*)d_in[9];
  const float* fc2_w  = (const float*)d_in[10];
  const float* fc2_b  = (const float*)d_in[11];
  float* out = (float*)d_out;
  float* ws  = (float*)d_ws;

  // field: 16*255*32*256 f16 = 33,423,360 halves = 16,711,680 floats (~64 MiB)
  _Float16* field = (_Float16*)ws;
  float* Gbuf  = ws + 16711680;                        // NROWS*24 = 3,133,440
  float* Xf    = Gbuf + (size_t)NROWS*24;              // 294,912
  float* parts = Xf   + (size_t)BATCH*CH*KY24*M2*2;    // 261,120
  float* bnpF  = parts + (size_t)64*BATCH*HH;          // 64 (per-layer fuse BN)
  float* bnpL  = bnpF + 64;                            // 64 (final BN)
  _Float16* Whi = (_Float16*)(bnpL + 64);              // 8192 halves each
  _Float16* Wlo = Whi + 2*8*64*8;
  _Float16* Th  = Wlo + 2*8*64*8;
  _Float16* Tl  = Th  + 16*64*8;
  _Float16* W1h = Tl  + 16*64*8;                       // 4096 halves each
  _Float16* W1l = W1h + 8*64*8;

  k_tabs<<<10, 256, 0, stream>>>(fc1_w, Whi, Wlo, Th, Tl, W1h, W1l);
  k_fc0<<<dim3(HH, BATCH), 256, 0, stream>>>(x, fc0_w, fc0_b, field);

  const size_t wstride = (size_t)2*CH*CH*M1*M2*2;      // per-layer spec_w elems
  for (int l=0; l<4; l++){
    int l0 = (l == 0);
    int relu = (l >= 1);                               // ReLU after layers 0..2
    const float* gg = l0 ? bn_g : bn_g + (size_t)(l-1)*CH;
    const float* gb = l0 ? bn_b : bn_b + (size_t)(l-1)*CH;
    k_fwd  <<<BATCH*CH, 256, 0, stream>>>(field, Xf, Whi, Wlo,
                                          parts, gg, gb, bnpF, l0, relu);
    k_specmix<<<dim3(CH, BATCH), 256, 0, stream>>>(Xf, spec_w + (size_t)l*wstride, Gbuf);
    k_fuse <<<dim3(HH, BATCH), 256, 0, stream>>>(field, Gbuf, conv_w + l*CH*CH,
                                                 conv_b + l*CH, field, parts,
                                                 Th, Tl, bnpF, relu);
  }
  k_stats<<<CH, 512, 0, stream>>>(parts, bn_g + 3*CH, bn_b + 3*CH, bnpL);
  k_final<<<dim3(SS, BATCH), 256, 0, stream>>>(field, bnpL, W1h, W1l,
                                               fc1_b, fc2_w, fc2_b, out);
}